// Round 7
// baseline (1180.749 us; speedup 1.0000x reference)
//
#include <hip/hip_runtime.h>
#include <hip/hip_bf16.h>

#define N_USERS 100000
#define N_ITEMS 50000
#define N_TOTAL 150000
#define NNZ     4000000
#define ALPHA_F 0.8f
#define ELL_CAP 128   // max row degree ~70 (Poisson(40), 50K items); 128 = 2 regs/lane

#define G_GEMM 782    // (N_ITEMS+63)/64
#define G_COPY 512
#define G_SCAT 1024

typedef __attribute__((ext_vector_type(8))) short bf16x8;
typedef __attribute__((ext_vector_type(4))) float f32x4;

static __device__ __forceinline__ short f2bf(float f) {
    unsigned u = __builtin_bit_cast(unsigned, f);
    unsigned r = (u + 0x7fff + ((u >> 16) & 1)) >> 16;   // RTNE
    return (short)r;
}
static __device__ __forceinline__ unsigned pack_bf2(float a, float b) {
    return (unsigned)(unsigned short)f2bf(a) | ((unsigned)(unsigned short)f2bf(b) << 16);
}
static __device__ __forceinline__ float bf_lo(unsigned u) { return __uint_as_float(u << 16); }
static __device__ __forceinline__ float bf_hi(unsigned u) { return __uint_as_float(u & 0xFFFF0000u); }

// ---------------------------------------------------------------- prep: zero cnt + W transposes

__global__ __launch_bounds__(256) void prep_kernel(const float* __restrict__ Wimg,
                                                   const float* __restrict__ Wtxt,
                                                   int* __restrict__ cnt,
                                                   short* __restrict__ Wti,
                                                   short* __restrict__ Wtt) {
    const int T0 = N_TOTAL;
    const int T1 = T0 + 4096 * 64;
    const int T2 = T1 + 384 * 64;
    int i = blockIdx.x * 256 + threadIdx.x;
    int stride = gridDim.x * 256;
    for (; i < T2; i += stride) {
        if (i < T0) {
            cnt[i] = 0;
        } else if (i < T1) {
            int idx = i - T0; int k = idx >> 6, n = idx & 63;
            Wti[(size_t)n * 4096 + k] = f2bf(Wimg[(size_t)k * 64 + n]);
        } else {
            int idx = i - T1; int k = idx >> 6, n = idx & 63;
            Wtt[(size_t)n * 384 + k] = f2bf(Wtxt[(size_t)k * 64 + n]);
        }
    }
}

// ---------------------------------------------------------------- mega kernel
// [0, G_GEMM):            item GEMM + bias + l2norm -> bf16 mirror item rows
// [G_GEMM, +G_COPY):      user pref -> bf16 mirror user rows
// [.., +G_SCAT):          ELL scatter (atomic slot per row; order fixed by sort later)

__global__ __launch_bounds__(256) void mega_kernel(
        const float* __restrict__ Aimg, const float* __restrict__ Atxt,
        const short* __restrict__ Wti, const short* __restrict__ Wtt,
        const float* __restrict__ bimg, const float* __restrict__ btxt,
        unsigned* __restrict__ egob,                     // [N_TOTAL*64] mirror
        const int* __restrict__ rows, const int* __restrict__ cols,
        const float* __restrict__ vals, int* __restrict__ cnt, int2* __restrict__ ell,
        const float* __restrict__ img_pref, const float* __restrict__ txt_pref) {
    int b = blockIdx.x;
    if (b < G_GEMM) {
        const int M = N_ITEMS;
        int t = threadIdx.x;
        int wave = t >> 6, l = t & 63;
        int col = l & 15;
        int kb  = l >> 4;
        int row0 = b * 64 + wave * 16;
        int arow = row0 + col;
        bool rowok = arow < M;

        f32x4 ai0 = {0,0,0,0}, ai1 = ai0, ai2 = ai0, ai3 = ai0;
        f32x4 at0 = ai0, at1 = ai0, at2 = ai0, at3 = ai0;

        {   // image: K = 4096
            const float* Ap = Aimg + (size_t)arow * 4096 + kb * 8;
            const short* Wp = Wti + (size_t)col * 4096 + kb * 8;
            for (int k0 = 0; k0 < 4096; k0 += 32) {
                float4 a0 = make_float4(0,0,0,0), a1 = a0;
                if (rowok) {
                    a0 = *reinterpret_cast<const float4*>(Ap + k0);
                    a1 = *reinterpret_cast<const float4*>(Ap + k0 + 4);
                }
                bf16x8 af;
                af[0]=f2bf(a0.x); af[1]=f2bf(a0.y); af[2]=f2bf(a0.z); af[3]=f2bf(a0.w);
                af[4]=f2bf(a1.x); af[5]=f2bf(a1.y); af[6]=f2bf(a1.z); af[7]=f2bf(a1.w);
                bf16x8 b0 = *reinterpret_cast<const bf16x8*>(Wp + k0);
                bf16x8 b1 = *reinterpret_cast<const bf16x8*>(Wp + (size_t)16 * 4096 + k0);
                bf16x8 b2 = *reinterpret_cast<const bf16x8*>(Wp + (size_t)32 * 4096 + k0);
                bf16x8 b3 = *reinterpret_cast<const bf16x8*>(Wp + (size_t)48 * 4096 + k0);
                ai0 = __builtin_amdgcn_mfma_f32_16x16x32_bf16(af, b0, ai0, 0, 0, 0);
                ai1 = __builtin_amdgcn_mfma_f32_16x16x32_bf16(af, b1, ai1, 0, 0, 0);
                ai2 = __builtin_amdgcn_mfma_f32_16x16x32_bf16(af, b2, ai2, 0, 0, 0);
                ai3 = __builtin_amdgcn_mfma_f32_16x16x32_bf16(af, b3, ai3, 0, 0, 0);
            }
        }
        {   // text: K = 384
            const float* Ap = Atxt + (size_t)arow * 384 + kb * 8;
            const short* Wp = Wtt + (size_t)col * 384 + kb * 8;
            for (int k0 = 0; k0 < 384; k0 += 32) {
                float4 a0 = make_float4(0,0,0,0), a1 = a0;
                if (rowok) {
                    a0 = *reinterpret_cast<const float4*>(Ap + k0);
                    a1 = *reinterpret_cast<const float4*>(Ap + k0 + 4);
                }
                bf16x8 af;
                af[0]=f2bf(a0.x); af[1]=f2bf(a0.y); af[2]=f2bf(a0.z); af[3]=f2bf(a0.w);
                af[4]=f2bf(a1.x); af[5]=f2bf(a1.y); af[6]=f2bf(a1.z); af[7]=f2bf(a1.w);
                bf16x8 b0 = *reinterpret_cast<const bf16x8*>(Wp + k0);
                bf16x8 b1 = *reinterpret_cast<const bf16x8*>(Wp + (size_t)16 * 384 + k0);
                bf16x8 b2 = *reinterpret_cast<const bf16x8*>(Wp + (size_t)32 * 384 + k0);
                bf16x8 b3 = *reinterpret_cast<const bf16x8*>(Wp + (size_t)48 * 384 + k0);
                at0 = __builtin_amdgcn_mfma_f32_16x16x32_bf16(af, b0, at0, 0, 0, 0);
                at1 = __builtin_amdgcn_mfma_f32_16x16x32_bf16(af, b1, at1, 0, 0, 0);
                at2 = __builtin_amdgcn_mfma_f32_16x16x32_bf16(af, b2, at2, 0, 0, 0);
                at3 = __builtin_amdgcn_mfma_f32_16x16x32_bf16(af, b3, at3, 0, 0, 0);
            }
        }

        float bi0 = bimg[ 0 + col], bi1 = bimg[16 + col], bi2 = bimg[32 + col], bi3 = bimg[48 + col];
        float bt0 = btxt[ 0 + col], bt1 = btxt[16 + col], bt2 = btxt[32 + col], bt3 = btxt[48 + col];
        #pragma unroll
        for (int i = 0; i < 4; ++i) {
            ai0[i] += bi0; ai1[i] += bi1; ai2[i] += bi2; ai3[i] += bi3;
            at0[i] += bt0; at1[i] += bt1; at2[i] += bt2; at3[i] += bt3;
        }
        unsigned* egob_items = egob + (size_t)N_USERS * 64;
        #pragma unroll
        for (int i = 0; i < 4; ++i) {
            float ssi = ai0[i]*ai0[i] + ai1[i]*ai1[i] + ai2[i]*ai2[i] + ai3[i]*ai3[i];
            float sst = at0[i]*at0[i] + at1[i]*at1[i] + at2[i]*at2[i] + at3[i]*at3[i];
            #pragma unroll
            for (int off = 1; off < 16; off <<= 1) {
                ssi += __shfl_xor(ssi, off, 64);
                sst += __shfl_xor(sst, off, 64);
            }
            float rni = 1.0f / fmaxf(sqrtf(ssi), 1e-12f);
            float rnt = 1.0f / fmaxf(sqrtf(sst), 1e-12f);
            int r = row0 + kb * 4 + i;
            if (r < M) {
                unsigned* ob = egob_items + (size_t)r * 64 + col;
                ob[ 0] = pack_bf2(ai0[i]*rni, at0[i]*rnt);
                ob[16] = pack_bf2(ai1[i]*rni, at1[i]*rnt);
                ob[32] = pack_bf2(ai2[i]*rni, at2[i]*rnt);
                ob[48] = pack_bf2(ai3[i]*rni, at3[i]*rnt);
            }
        }
    } else if (b < G_GEMM + G_COPY) {
        int idx = (b - G_GEMM) * 256 + threadIdx.x;
        int stride = G_COPY * 256;
        for (; idx < N_USERS * 16; idx += stride) {
            int row = idx >> 4, w4 = (idx & 15) << 2;
            float4 iv = *reinterpret_cast<const float4*>(&img_pref[(size_t)row * 64 + w4]);
            float4 tv = *reinterpret_cast<const float4*>(&txt_pref[(size_t)row * 64 + w4]);
            uint4 m;
            m.x = pack_bf2(iv.x, tv.x); m.y = pack_bf2(iv.y, tv.y);
            m.z = pack_bf2(iv.z, tv.z); m.w = pack_bf2(iv.w, tv.w);
            *reinterpret_cast<uint4*>(&egob[(size_t)row * 64 + w4]) = m;
        }
    } else {
        int i = (b - G_GEMM - G_COPY) * 256 + threadIdx.x;
        int stride = G_SCAT * 256;
        for (; i < NNZ; i += stride) {
            int r = rows[i];
            int p = atomicAdd(&cnt[r], 1);
            if (p < ELL_CAP)
                ell[(size_t)r * ELL_CAP + p] = make_int2(cols[i], __float_as_int(vals[i]));
        }
    }
}

// ---------------------------------------------------------------- per-row slot sort
// Bitonic sort of each row's ELL slots by col id (one 64-lane wave per row,
// 128-element network, 2 elements per lane: idx0=lane, idx1=lane+64).
// Duplicate edges carry identical (col,val), so the sorted sequence is unique ->
// bit-deterministic SpMM sums regardless of atomicAdd arbitration order.

__global__ __launch_bounds__(256) void sort_kernel(const int* __restrict__ cnt,
                                                   int2* __restrict__ ell) {
    int row = blockIdx.x * 4 + (threadIdx.x >> 6);
    if (row >= N_TOTAL) return;
    int lane = threadIdx.x & 63;
    int deg = min(cnt[row], ELL_CAP);
    if (deg <= 1) return;
    int2* base = ell + (size_t)row * ELL_CAP;
    int2 e0 = (lane < deg)      ? base[lane]      : make_int2(0x7FFFFFFF, 0);
    int2 e1 = (lane + 64 < deg) ? base[lane + 64] : make_int2(0x7FFFFFFF, 0);
    #pragma unroll
    for (int k = 2; k <= 128; k <<= 1) {
        #pragma unroll
        for (int j = 64; j >= 1; j >>= 1) {
            if (j >= k) continue;
            if (j == 64) {
                // partner of idx0=lane is idx1=lane+64 (same thread); k==128 -> ascending
                if (e0.x > e1.x) { int2 tmp = e0; e0 = e1; e1 = tmp; }
            } else {
                int2 p0, p1;
                p0.x = __shfl_xor(e0.x, j, 64); p0.y = __shfl_xor(e0.y, j, 64);
                p1.x = __shfl_xor(e1.x, j, 64); p1.y = __shfl_xor(e1.y, j, 64);
                bool up0 = ((lane & k) == 0);          // idx0 = lane
                bool up1 = (((lane + 64) & k) == 0);   // idx1 = lane + 64
                bool lo0 = ((lane & j) == 0);
                bool lo1 = lo0;                        // bit j<64 identical for idx0/idx1
                bool keepmin0 = (up0 == lo0);
                bool keepmin1 = (up1 == lo1);
                if (keepmin0 ? (e0.x > p0.x) : (e0.x < p0.x)) e0 = p0;
                if (keepmin1 ? (e1.x > p1.x) : (e1.x < p1.x)) e1 = p1;
            }
        }
    }
    if (lane < deg)      base[lane]      = e0;
    if (lane + 64 < deg) base[lane + 64] = e1;
}

// ---------------------------------------------------------------- SpMM layer (bf16 state)
// lane handles dims (lane, lane+64); self + gathers from bf16 mirror.

__global__ __launch_bounds__(256) void spmm_kernel(
        const int* __restrict__ cnt, const int2* __restrict__ ell,
        const unsigned* __restrict__ xb,
        float* __restrict__ out32, unsigned* __restrict__ outb) {
    int row = blockIdx.x * 4 + (threadIdx.x >> 6);
    if (row >= N_TOTAL) return;
    int lane = threadIdx.x & 63;
    unsigned sw = xb[(size_t)row * 64 + lane];
    float2 acc;
    acc.x = ALPHA_F * bf_lo(sw);
    acc.y = ALPHA_F * bf_hi(sw);
    int deg = min(cnt[row], ELL_CAP);
    const int2* base = ell + (size_t)row * ELL_CAP;
    int i = 0;
    for (; i + 8 <= deg; i += 8) {
        int4 p0 = *reinterpret_cast<const int4*>(base + i);
        int4 p1 = *reinterpret_cast<const int4*>(base + i + 2);
        int4 p2 = *reinterpret_cast<const int4*>(base + i + 4);
        int4 p3 = *reinterpret_cast<const int4*>(base + i + 6);
        unsigned g0 = xb[(size_t)p0.x * 64 + lane];
        unsigned g1 = xb[(size_t)p0.z * 64 + lane];
        unsigned g2 = xb[(size_t)p1.x * 64 + lane];
        unsigned g3 = xb[(size_t)p1.z * 64 + lane];
        unsigned g4 = xb[(size_t)p2.x * 64 + lane];
        unsigned g5 = xb[(size_t)p2.z * 64 + lane];
        unsigned g6 = xb[(size_t)p3.x * 64 + lane];
        unsigned g7 = xb[(size_t)p3.z * 64 + lane];
        float v0 = __int_as_float(p0.y), v1 = __int_as_float(p0.w);
        float v2 = __int_as_float(p1.y), v3 = __int_as_float(p1.w);
        float v4 = __int_as_float(p2.y), v5 = __int_as_float(p2.w);
        float v6 = __int_as_float(p3.y), v7 = __int_as_float(p3.w);
        acc.x = fmaf(v0, bf_lo(g0), acc.x); acc.y = fmaf(v0, bf_hi(g0), acc.y);
        acc.x = fmaf(v1, bf_lo(g1), acc.x); acc.y = fmaf(v1, bf_hi(g1), acc.y);
        acc.x = fmaf(v2, bf_lo(g2), acc.x); acc.y = fmaf(v2, bf_hi(g2), acc.y);
        acc.x = fmaf(v3, bf_lo(g3), acc.x); acc.y = fmaf(v3, bf_hi(g3), acc.y);
        acc.x = fmaf(v4, bf_lo(g4), acc.x); acc.y = fmaf(v4, bf_hi(g4), acc.y);
        acc.x = fmaf(v5, bf_lo(g5), acc.x); acc.y = fmaf(v5, bf_hi(g5), acc.y);
        acc.x = fmaf(v6, bf_lo(g6), acc.x); acc.y = fmaf(v6, bf_hi(g6), acc.y);
        acc.x = fmaf(v7, bf_lo(g7), acc.x); acc.y = fmaf(v7, bf_hi(g7), acc.y);
    }
    for (; i < deg; ++i) {
        int2 c = base[i];
        float v = __int_as_float(c.y);
        unsigned g = xb[(size_t)c.x * 64 + lane];
        acc.x = fmaf(v, bf_lo(g), acc.x);
        acc.y = fmaf(v, bf_hi(g), acc.y);
    }
    if (out32) {
        out32[(size_t)row * 128 + lane] = acc.x;
        out32[(size_t)row * 128 + 64 + lane] = acc.y;
    }
    if (outb)
        outb[(size_t)row * 64 + lane] = pack_bf2(acc.x, acc.y);
}

// ---------------------------------------------------------------- launch

extern "C" void kernel_launch(void* const* d_in, const int* in_sizes, int n_in,
                              void* d_out, int out_size, void* d_ws, size_t ws_size,
                              hipStream_t stream) {
    const float* image_feats = (const float*)d_in[0];
    const float* text_feats  = (const float*)d_in[1];
    const float* image_pref  = (const float*)d_in[2];
    const float* text_pref   = (const float*)d_in[3];
    const float* W_img       = (const float*)d_in[4];
    const float* b_img       = (const float*)d_in[5];
    const float* W_txt       = (const float*)d_in[6];
    const float* b_txt       = (const float*)d_in[7];
    const float* adj_vals    = (const float*)d_in[8];
    const int*   adj_rows    = (const int*)d_in[9];
    const int*   adj_cols    = (const int*)d_in[10];

    float* out = (float*)d_out;                          // [150000*128]

    char* ws = (char*)d_ws;
    size_t off = 0;
    auto alloc = [&](size_t bytes) { char* p = ws + off; off += (bytes + 255) & ~size_t(255); return p; };
    int*      cnt    = (int*)     alloc(N_TOTAL * sizeof(int));
    int2*     ell    = (int2*)    alloc((size_t)N_TOTAL * ELL_CAP * sizeof(int2));
    unsigned* m0     = (unsigned*)alloc((size_t)N_TOTAL * 64 * sizeof(unsigned));
    unsigned* m1     = (unsigned*)alloc((size_t)N_TOTAL * 64 * sizeof(unsigned));
    short*    Wt_img = (short*)   alloc((size_t)64 * 4096 * sizeof(short));
    short*    Wt_txt = (short*)   alloc((size_t)64 * 384 * sizeof(short));
    (void)ws_size; (void)out_size; (void)n_in; (void)in_sizes;

    // --- prep: zero cnt + bf16 W transposes ---
    prep_kernel<<<512, 256, 0, stream>>>(W_img, W_txt, cnt, Wt_img, Wt_txt);

    // --- mega: item GEMM+norm -> m0  ||  user pref -> m0  ||  ELL scatter ---
    mega_kernel<<<G_GEMM + G_COPY + G_SCAT, 256, 0, stream>>>(
        image_feats, text_feats, Wt_img, Wt_txt, b_img, b_txt, m0,
        adj_rows, adj_cols, adj_vals, cnt, ell, image_pref, text_pref);

    // --- canonicalize ELL slot order (bit-determinism across calls) ---
    const int ROW_GRID = (N_TOTAL + 3) / 4;
    sort_kernel<<<ROW_GRID, 256, 0, stream>>>(cnt, ell);

    // --- 3 propagation layers (bf16 state; final layer writes f32 d_out) ---
    spmm_kernel<<<ROW_GRID, 256, 0, stream>>>(cnt, ell, m0, nullptr, m1);
    spmm_kernel<<<ROW_GRID, 256, 0, stream>>>(cnt, ell, m1, nullptr, m0);
    spmm_kernel<<<ROW_GRID, 256, 0, stream>>>(cnt, ell, m0, out, nullptr);
}

// Round 8
// 1158.484 us; speedup vs baseline: 1.0192x; 1.0192x over previous
//
#include <hip/hip_runtime.h>
#include <hip/hip_bf16.h>

#define N_USERS 100000
#define N_ITEMS 50000
#define N_TOTAL 150000
#define NNZ     4000000
#define ALPHA_F 0.8f
#define ELL_CAP 128   // max row degree ~70 (users ~Poisson(20), items ~Poisson(40))

#define G_GEMM 782    // (N_ITEMS+63)/64
#define G_COPY 512
#define G_SCAT 1024

typedef __attribute__((ext_vector_type(8))) short bf16x8;
typedef __attribute__((ext_vector_type(4))) float f32x4;

static __device__ __forceinline__ short f2bf(float f) {
    unsigned u = __builtin_bit_cast(unsigned, f);
    unsigned r = (u + 0x7fff + ((u >> 16) & 1)) >> 16;   // RTNE
    return (short)r;
}
static __device__ __forceinline__ unsigned pack_bf2(float a, float b) {
    return (unsigned)(unsigned short)f2bf(a) | ((unsigned)(unsigned short)f2bf(b) << 16);
}
static __device__ __forceinline__ float bf_lo(unsigned u) { return __uint_as_float(u << 16); }
static __device__ __forceinline__ float bf_hi(unsigned u) { return __uint_as_float(u & 0xFFFF0000u); }

// ---------------------------------------------------------------- prep: zero cnt + W transposes

__global__ __launch_bounds__(256) void prep_kernel(const float* __restrict__ Wimg,
                                                   const float* __restrict__ Wtxt,
                                                   int* __restrict__ cnt,
                                                   short* __restrict__ Wti,
                                                   short* __restrict__ Wtt) {
    const int T0 = N_TOTAL;
    const int T1 = T0 + 4096 * 64;
    const int T2 = T1 + 384 * 64;
    int i = blockIdx.x * 256 + threadIdx.x;
    int stride = gridDim.x * 256;
    for (; i < T2; i += stride) {
        if (i < T0) {
            cnt[i] = 0;
        } else if (i < T1) {
            int idx = i - T0; int k = idx >> 6, n = idx & 63;
            Wti[(size_t)n * 4096 + k] = f2bf(Wimg[(size_t)k * 64 + n]);
        } else {
            int idx = i - T1; int k = idx >> 6, n = idx & 63;
            Wtt[(size_t)n * 384 + k] = f2bf(Wtxt[(size_t)k * 64 + n]);
        }
    }
}

// ---------------------------------------------------------------- mega kernel
// [0, G_GEMM):        item GEMM + bias + l2norm -> bf16 mirror item rows
// [G_GEMM, +G_COPY):  user pref -> bf16 mirror user rows
// [.., +G_SCAT):      ELL scatter (atomic slot per row; order canonicalized by sort)
// GEMM A-loads batched 4 k-steps deep (8 dwordx4 in flight = 8KB/wave) for MLP.

__global__ __launch_bounds__(256) void mega_kernel(
        const float* __restrict__ Aimg, const float* __restrict__ Atxt,
        const short* __restrict__ Wti, const short* __restrict__ Wtt,
        const float* __restrict__ bimg, const float* __restrict__ btxt,
        unsigned* __restrict__ egob,                     // [N_TOTAL*64] mirror
        const int* __restrict__ rows, const int* __restrict__ cols,
        const float* __restrict__ vals, int* __restrict__ cnt, int2* __restrict__ ell,
        const float* __restrict__ img_pref, const float* __restrict__ txt_pref) {
    int b = blockIdx.x;
    if (b < G_GEMM) {
        const int M = N_ITEMS;
        int t = threadIdx.x;
        int wave = t >> 6, l = t & 63;
        int col = l & 15;
        int kb  = l >> 4;
        int row0 = b * 64 + wave * 16;
        int arow = row0 + col;
        bool rowok = arow < M;

        f32x4 ai0 = {0,0,0,0}, ai1 = ai0, ai2 = ai0, ai3 = ai0;
        f32x4 at0 = ai0, at1 = ai0, at2 = ai0, at3 = ai0;

        {   // image: K = 4096, 4 MFMA-k-steps (128 k) per batch
            const float* Ap = Aimg + (size_t)arow * 4096 + kb * 8;
            const short* Wp = Wti + (size_t)col * 4096 + kb * 8;
            for (int k0 = 0; k0 < 4096; k0 += 128) {
                float4 a[8];
                #pragma unroll
                for (int s = 0; s < 4; ++s) {
                    if (rowok) {
                        a[2*s]   = *reinterpret_cast<const float4*>(Ap + k0 + 32*s);
                        a[2*s+1] = *reinterpret_cast<const float4*>(Ap + k0 + 32*s + 4);
                    } else {
                        a[2*s]   = make_float4(0,0,0,0);
                        a[2*s+1] = make_float4(0,0,0,0);
                    }
                }
                #pragma unroll
                for (int s = 0; s < 4; ++s) {
                    bf16x8 af;
                    af[0]=f2bf(a[2*s].x);   af[1]=f2bf(a[2*s].y);
                    af[2]=f2bf(a[2*s].z);   af[3]=f2bf(a[2*s].w);
                    af[4]=f2bf(a[2*s+1].x); af[5]=f2bf(a[2*s+1].y);
                    af[6]=f2bf(a[2*s+1].z); af[7]=f2bf(a[2*s+1].w);
                    const short* wp = Wp + k0 + 32*s;
                    bf16x8 b0 = *reinterpret_cast<const bf16x8*>(wp);
                    bf16x8 b1 = *reinterpret_cast<const bf16x8*>(wp + (size_t)16 * 4096);
                    bf16x8 b2 = *reinterpret_cast<const bf16x8*>(wp + (size_t)32 * 4096);
                    bf16x8 b3 = *reinterpret_cast<const bf16x8*>(wp + (size_t)48 * 4096);
                    ai0 = __builtin_amdgcn_mfma_f32_16x16x32_bf16(af, b0, ai0, 0, 0, 0);
                    ai1 = __builtin_amdgcn_mfma_f32_16x16x32_bf16(af, b1, ai1, 0, 0, 0);
                    ai2 = __builtin_amdgcn_mfma_f32_16x16x32_bf16(af, b2, ai2, 0, 0, 0);
                    ai3 = __builtin_amdgcn_mfma_f32_16x16x32_bf16(af, b3, ai3, 0, 0, 0);
                }
            }
        }
        {   // text: K = 384, same batched pattern (3 batches)
            const float* Ap = Atxt + (size_t)arow * 384 + kb * 8;
            const short* Wp = Wtt + (size_t)col * 384 + kb * 8;
            for (int k0 = 0; k0 < 384; k0 += 128) {
                float4 a[8];
                #pragma unroll
                for (int s = 0; s < 4; ++s) {
                    if (rowok) {
                        a[2*s]   = *reinterpret_cast<const float4*>(Ap + k0 + 32*s);
                        a[2*s+1] = *reinterpret_cast<const float4*>(Ap + k0 + 32*s + 4);
                    } else {
                        a[2*s]   = make_float4(0,0,0,0);
                        a[2*s+1] = make_float4(0,0,0,0);
                    }
                }
                #pragma unroll
                for (int s = 0; s < 4; ++s) {
                    bf16x8 af;
                    af[0]=f2bf(a[2*s].x);   af[1]=f2bf(a[2*s].y);
                    af[2]=f2bf(a[2*s].z);   af[3]=f2bf(a[2*s].w);
                    af[4]=f2bf(a[2*s+1].x); af[5]=f2bf(a[2*s+1].y);
                    af[6]=f2bf(a[2*s+1].z); af[7]=f2bf(a[2*s+1].w);
                    const short* wp = Wp + k0 + 32*s;
                    bf16x8 b0 = *reinterpret_cast<const bf16x8*>(wp);
                    bf16x8 b1 = *reinterpret_cast<const bf16x8*>(wp + (size_t)16 * 384);
                    bf16x8 b2 = *reinterpret_cast<const bf16x8*>(wp + (size_t)32 * 384);
                    bf16x8 b3 = *reinterpret_cast<const bf16x8*>(wp + (size_t)48 * 384);
                    at0 = __builtin_amdgcn_mfma_f32_16x16x32_bf16(af, b0, at0, 0, 0, 0);
                    at1 = __builtin_amdgcn_mfma_f32_16x16x32_bf16(af, b1, at1, 0, 0, 0);
                    at2 = __builtin_amdgcn_mfma_f32_16x16x32_bf16(af, b2, at2, 0, 0, 0);
                    at3 = __builtin_amdgcn_mfma_f32_16x16x32_bf16(af, b3, at3, 0, 0, 0);
                }
            }
        }

        float bi0 = bimg[ 0 + col], bi1 = bimg[16 + col], bi2 = bimg[32 + col], bi3 = bimg[48 + col];
        float bt0 = btxt[ 0 + col], bt1 = btxt[16 + col], bt2 = btxt[32 + col], bt3 = btxt[48 + col];
        #pragma unroll
        for (int i = 0; i < 4; ++i) {
            ai0[i] += bi0; ai1[i] += bi1; ai2[i] += bi2; ai3[i] += bi3;
            at0[i] += bt0; at1[i] += bt1; at2[i] += bt2; at3[i] += bt3;
        }
        unsigned* egob_items = egob + (size_t)N_USERS * 64;
        #pragma unroll
        for (int i = 0; i < 4; ++i) {
            float ssi = ai0[i]*ai0[i] + ai1[i]*ai1[i] + ai2[i]*ai2[i] + ai3[i]*ai3[i];
            float sst = at0[i]*at0[i] + at1[i]*at1[i] + at2[i]*at2[i] + at3[i]*at3[i];
            #pragma unroll
            for (int off = 1; off < 16; off <<= 1) {
                ssi += __shfl_xor(ssi, off, 64);
                sst += __shfl_xor(sst, off, 64);
            }
            float rni = 1.0f / fmaxf(sqrtf(ssi), 1e-12f);
            float rnt = 1.0f / fmaxf(sqrtf(sst), 1e-12f);
            int r = row0 + kb * 4 + i;
            if (r < M) {
                unsigned* ob = egob_items + (size_t)r * 64 + col;
                ob[ 0] = pack_bf2(ai0[i]*rni, at0[i]*rnt);
                ob[16] = pack_bf2(ai1[i]*rni, at1[i]*rnt);
                ob[32] = pack_bf2(ai2[i]*rni, at2[i]*rnt);
                ob[48] = pack_bf2(ai3[i]*rni, at3[i]*rnt);
            }
        }
    } else if (b < G_GEMM + G_COPY) {
        int idx = (b - G_GEMM) * 256 + threadIdx.x;
        int stride = G_COPY * 256;
        for (; idx < N_USERS * 16; idx += stride) {
            int row = idx >> 4, w4 = (idx & 15) << 2;
            float4 iv = *reinterpret_cast<const float4*>(&img_pref[(size_t)row * 64 + w4]);
            float4 tv = *reinterpret_cast<const float4*>(&txt_pref[(size_t)row * 64 + w4]);
            uint4 m;
            m.x = pack_bf2(iv.x, tv.x); m.y = pack_bf2(iv.y, tv.y);
            m.z = pack_bf2(iv.z, tv.z); m.w = pack_bf2(iv.w, tv.w);
            *reinterpret_cast<uint4*>(&egob[(size_t)row * 64 + w4]) = m;
        }
    } else {
        int i = (b - G_GEMM - G_COPY) * 256 + threadIdx.x;
        int stride = G_SCAT * 256;
        for (; i < NNZ; i += stride) {
            int r = rows[i];
            int p = atomicAdd(&cnt[r], 1);
            if (p < ELL_CAP)
                ell[(size_t)r * ELL_CAP + p] = make_int2(cols[i], __float_as_int(vals[i]));
        }
    }
}

// ---------------------------------------------------------------- per-row slot sort
// Bitonic sort of each row's ELL slots by col id (one 64-lane wave per row,
// 128-element network, 2 elems/lane). Duplicate edges carry identical (col,val),
// so the sorted sequence is unique -> bit-deterministic SpMM sums.

__global__ __launch_bounds__(256) void sort_kernel(const int* __restrict__ cnt,
                                                   int2* __restrict__ ell) {
    int row = blockIdx.x * 4 + (threadIdx.x >> 6);
    if (row >= N_TOTAL) return;
    int lane = threadIdx.x & 63;
    int deg = min(cnt[row], ELL_CAP);
    if (deg <= 1) return;
    int2* base = ell + (size_t)row * ELL_CAP;
    int2 e0 = (lane < deg)      ? base[lane]      : make_int2(0x7FFFFFFF, 0);
    int2 e1 = (lane + 64 < deg) ? base[lane + 64] : make_int2(0x7FFFFFFF, 0);
    #pragma unroll
    for (int k = 2; k <= 128; k <<= 1) {
        #pragma unroll
        for (int j = 64; j >= 1; j >>= 1) {
            if (j >= k) continue;
            if (j == 64) {
                if (e0.x > e1.x) { int2 tmp = e0; e0 = e1; e1 = tmp; }
            } else {
                int2 p0, p1;
                p0.x = __shfl_xor(e0.x, j, 64); p0.y = __shfl_xor(e0.y, j, 64);
                p1.x = __shfl_xor(e1.x, j, 64); p1.y = __shfl_xor(e1.y, j, 64);
                bool up0 = ((lane & k) == 0);
                bool up1 = (((lane + 64) & k) == 0);
                bool lo0 = ((lane & j) == 0);
                bool keepmin0 = (up0 == lo0);
                bool keepmin1 = (up1 == lo0);
                if (keepmin0 ? (e0.x > p0.x) : (e0.x < p0.x)) e0 = p0;
                if (keepmin1 ? (e1.x > p1.x) : (e1.x < p1.x)) e1 = p1;
            }
        }
    }
    if (lane < deg)      base[lane]      = e0;
    if (lane + 64 < deg) base[lane + 64] = e1;
}

// ---------------------------------------------------------------- SpMM layer (bf16 state)
// lane handles dims (lane, lane+64); self + gathers from bf16 mirror.

__global__ __launch_bounds__(256) void spmm_kernel(
        const int* __restrict__ cnt, const int2* __restrict__ ell,
        const unsigned* __restrict__ xb,
        float* __restrict__ out32, unsigned* __restrict__ outb) {
    int row = blockIdx.x * 4 + (threadIdx.x >> 6);
    if (row >= N_TOTAL) return;
    int lane = threadIdx.x & 63;
    unsigned sw = xb[(size_t)row * 64 + lane];
    float2 acc;
    acc.x = ALPHA_F * bf_lo(sw);
    acc.y = ALPHA_F * bf_hi(sw);
    int deg = min(cnt[row], ELL_CAP);
    const int2* base = ell + (size_t)row * ELL_CAP;
    int i = 0;
    for (; i + 8 <= deg; i += 8) {
        int4 p0 = *reinterpret_cast<const int4*>(base + i);
        int4 p1 = *reinterpret_cast<const int4*>(base + i + 2);
        int4 p2 = *reinterpret_cast<const int4*>(base + i + 4);
        int4 p3 = *reinterpret_cast<const int4*>(base + i + 6);
        unsigned g0 = xb[(size_t)p0.x * 64 + lane];
        unsigned g1 = xb[(size_t)p0.z * 64 + lane];
        unsigned g2 = xb[(size_t)p1.x * 64 + lane];
        unsigned g3 = xb[(size_t)p1.z * 64 + lane];
        unsigned g4 = xb[(size_t)p2.x * 64 + lane];
        unsigned g5 = xb[(size_t)p2.z * 64 + lane];
        unsigned g6 = xb[(size_t)p3.x * 64 + lane];
        unsigned g7 = xb[(size_t)p3.z * 64 + lane];
        float v0 = __int_as_float(p0.y), v1 = __int_as_float(p0.w);
        float v2 = __int_as_float(p1.y), v3 = __int_as_float(p1.w);
        float v4 = __int_as_float(p2.y), v5 = __int_as_float(p2.w);
        float v6 = __int_as_float(p3.y), v7 = __int_as_float(p3.w);
        acc.x = fmaf(v0, bf_lo(g0), acc.x); acc.y = fmaf(v0, bf_hi(g0), acc.y);
        acc.x = fmaf(v1, bf_lo(g1), acc.x); acc.y = fmaf(v1, bf_hi(g1), acc.y);
        acc.x = fmaf(v2, bf_lo(g2), acc.x); acc.y = fmaf(v2, bf_hi(g2), acc.y);
        acc.x = fmaf(v3, bf_lo(g3), acc.x); acc.y = fmaf(v3, bf_hi(g3), acc.y);
        acc.x = fmaf(v4, bf_lo(g4), acc.x); acc.y = fmaf(v4, bf_hi(g4), acc.y);
        acc.x = fmaf(v5, bf_lo(g5), acc.x); acc.y = fmaf(v5, bf_hi(g5), acc.y);
        acc.x = fmaf(v6, bf_lo(g6), acc.x); acc.y = fmaf(v6, bf_hi(g6), acc.y);
        acc.x = fmaf(v7, bf_lo(g7), acc.x); acc.y = fmaf(v7, bf_hi(g7), acc.y);
    }
    for (; i < deg; ++i) {
        int2 c = base[i];
        float v = __int_as_float(c.y);
        unsigned g = xb[(size_t)c.x * 64 + lane];
        acc.x = fmaf(v, bf_lo(g), acc.x);
        acc.y = fmaf(v, bf_hi(g), acc.y);
    }
    if (out32) {
        out32[(size_t)row * 128 + lane] = acc.x;
        out32[(size_t)row * 128 + 64 + lane] = acc.y;
    }
    if (outb)
        outb[(size_t)row * 64 + lane] = pack_bf2(acc.x, acc.y);
}

// ---------------------------------------------------------------- launch

extern "C" void kernel_launch(void* const* d_in, const int* in_sizes, int n_in,
                              void* d_out, int out_size, void* d_ws, size_t ws_size,
                              hipStream_t stream) {
    const float* image_feats = (const float*)d_in[0];
    const float* text_feats  = (const float*)d_in[1];
    const float* image_pref  = (const float*)d_in[2];
    const float* text_pref   = (const float*)d_in[3];
    const float* W_img       = (const float*)d_in[4];
    const float* b_img       = (const float*)d_in[5];
    const float* W_txt       = (const float*)d_in[6];
    const float* b_txt       = (const float*)d_in[7];
    const float* adj_vals    = (const float*)d_in[8];
    const int*   adj_rows    = (const int*)d_in[9];
    const int*   adj_cols    = (const int*)d_in[10];

    float* out = (float*)d_out;                          // [150000*128]

    char* ws = (char*)d_ws;
    size_t off = 0;
    auto alloc = [&](size_t bytes) { char* p = ws + off; off += (bytes + 255) & ~size_t(255); return p; };
    int*      cnt    = (int*)     alloc(N_TOTAL * sizeof(int));
    int2*     ell    = (int2*)    alloc((size_t)N_TOTAL * ELL_CAP * sizeof(int2));
    unsigned* m0     = (unsigned*)alloc((size_t)N_TOTAL * 64 * sizeof(unsigned));
    unsigned* m1     = (unsigned*)alloc((size_t)N_TOTAL * 64 * sizeof(unsigned));
    short*    Wt_img = (short*)   alloc((size_t)64 * 4096 * sizeof(short));
    short*    Wt_txt = (short*)   alloc((size_t)64 * 384 * sizeof(short));
    (void)ws_size; (void)out_size; (void)n_in; (void)in_sizes;

    // --- prep: zero cnt + bf16 W transposes ---
    prep_kernel<<<512, 256, 0, stream>>>(W_img, W_txt, cnt, Wt_img, Wt_txt);

    // --- mega: item GEMM+norm -> m0  ||  user pref -> m0  ||  ELL scatter ---
    mega_kernel<<<G_GEMM + G_COPY + G_SCAT, 256, 0, stream>>>(
        image_feats, text_feats, Wt_img, Wt_txt, b_img, b_txt, m0,
        adj_rows, adj_cols, adj_vals, cnt, ell, image_pref, text_pref);

    // --- canonicalize ELL slot order (bit-determinism across calls) ---
    const int ROW_GRID = (N_TOTAL + 3) / 4;
    sort_kernel<<<ROW_GRID, 256, 0, stream>>>(cnt, ell);

    // --- 3 propagation layers (bf16 state; final layer writes f32 d_out) ---
    spmm_kernel<<<ROW_GRID, 256, 0, stream>>>(cnt, ell, m0, nullptr, m1);
    spmm_kernel<<<ROW_GRID, 256, 0, stream>>>(cnt, ell, m1, nullptr, m0);
    spmm_kernel<<<ROW_GRID, 256, 0, stream>>>(cnt, ell, m0, out, nullptr);
}

// Round 9
// 1140.547 us; speedup vs baseline: 1.0352x; 1.0157x over previous
//
#include <hip/hip_runtime.h>
#include <hip/hip_bf16.h>

#define N_USERS 100000
#define N_ITEMS 50000
#define N_TOTAL 150000
#define NNZ     4000000
#define ALPHA_F 0.8f
#define ELL_CAP 128   // max row degree ~70 (users ~Poisson(20), items ~Poisson(40))
#define KCHUNK  128

#define C_COPY 512
#define C_SCAT 1024

typedef __attribute__((ext_vector_type(8))) short bf16x8;
typedef __attribute__((ext_vector_type(4))) float f32x4;

static __device__ __forceinline__ short f2bf(float f) {
    unsigned u = __builtin_bit_cast(unsigned, f);
    unsigned r = (u + 0x7fff + ((u >> 16) & 1)) >> 16;   // RTNE
    return (short)r;
}
static __device__ __forceinline__ unsigned pack_bf2(float a, float b) {
    return (unsigned)(unsigned short)f2bf(a) | ((unsigned)(unsigned short)f2bf(b) << 16);
}
static __device__ __forceinline__ float bf_lo(unsigned u) { return __uint_as_float(u << 16); }
static __device__ __forceinline__ float bf_hi(unsigned u) { return __uint_as_float(u & 0xFFFF0000u); }

static __device__ __forceinline__ void gload_lds16(const void* src, void* dst) {
    __builtin_amdgcn_global_load_lds(
        (const __attribute__((address_space(1))) unsigned*)src,
        (__attribute__((address_space(3))) unsigned*)dst, 16, 0, 0);
}

// ---------------------------------------------------------------- prep: zero cnt + W transposes

__global__ __launch_bounds__(256) void prep_kernel(const float* __restrict__ Wimg,
                                                   const float* __restrict__ Wtxt,
                                                   int* __restrict__ cnt,
                                                   short* __restrict__ Wti,
                                                   short* __restrict__ Wtt) {
    const int T0 = N_TOTAL;
    const int T1 = T0 + 4096 * 64;
    const int T2 = T1 + 384 * 64;
    int i = blockIdx.x * 256 + threadIdx.x;
    int stride = gridDim.x * 256;
    for (; i < T2; i += stride) {
        if (i < T0) {
            cnt[i] = 0;
        } else if (i < T1) {
            int idx = i - T0; int k = idx >> 6, n = idx & 63;
            Wti[(size_t)n * 4096 + k] = f2bf(Wimg[(size_t)k * 64 + n]);
        } else {
            int idx = i - T1; int k = idx >> 6, n = idx & 63;
            Wtt[(size_t)n * 384 + k] = f2bf(Wtxt[(size_t)k * 64 + n]);
        }
    }
}

// ---------------------------------------------------------------- scatter + user copy

__global__ __launch_bounds__(256) void scat_copy_kernel(
        const int* __restrict__ rows, const int* __restrict__ cols,
        const float* __restrict__ vals, int* __restrict__ cnt, int2* __restrict__ ell,
        const float* __restrict__ img_pref, const float* __restrict__ txt_pref,
        unsigned* __restrict__ egob) {
    int b = blockIdx.x;
    if (b < C_COPY) {
        int idx = b * 256 + threadIdx.x;
        int stride = C_COPY * 256;
        for (; idx < N_USERS * 16; idx += stride) {
            int row = idx >> 4, w4 = (idx & 15) << 2;
            float4 iv = *reinterpret_cast<const float4*>(&img_pref[(size_t)row * 64 + w4]);
            float4 tv = *reinterpret_cast<const float4*>(&txt_pref[(size_t)row * 64 + w4]);
            uint4 m;
            m.x = pack_bf2(iv.x, tv.x); m.y = pack_bf2(iv.y, tv.y);
            m.z = pack_bf2(iv.z, tv.z); m.w = pack_bf2(iv.w, tv.w);
            *reinterpret_cast<uint4*>(&egob[(size_t)row * 64 + w4]) = m;
        }
    } else {
        int i = (b - C_COPY) * 256 + threadIdx.x;
        int stride = C_SCAT * 256;
        for (; i < NNZ; i += stride) {
            int r = rows[i];
            int p = atomicAdd(&cnt[r], 1);
            if (p < ELL_CAP)
                ell[(size_t)r * ELL_CAP + p] = make_int2(cols[i], __float_as_int(vals[i]));
        }
    }
}

// ---------------------------------------------------------------- GEMM via async-LDS staging
// Per block: 64 item rows. Double-buffered A (64x128 f32) and W (64x128 bf16) tiles,
// staged with global_load_lds (no VGPR pressure -> loads stay in flight).
// XOR-swizzled LDS layout (pre-swizzled global src + swizzled read; LDS linear):
//   A: physical slot X (16B units) of row r holds logical bytes X ^ ((r&7)<<4)
//   B: physical slot X of col c holds logical bytes X ^ ((c&15)<<4)
// MFMA 16x16x32 bf16; wave w computes rows 16w..16w+15, all 64 cols.

static __device__ __forceinline__ void compute_chunk(
        const float* at, const short* bt, int wave, int lane,
        f32x4& c0, f32x4& c1, f32x4& c2, f32x4& c3) {
    const int col = lane & 15, kb = lane >> 4;
    const int arow = 16 * wave + col;
    const int aswz = (col & 7) << 4;
    const int bswz = col << 4;
    const char* abase = (const char*)at + arow * 512;
    const char* bbase = (const char*)bt + col * 256;
    #pragma unroll
    for (int ks = 0; ks < 4; ++ks) {
        int Xa = ks * 128 + kb * 32;
        float4 a0v = *(const float4*)(abase + ((Xa)      ^ aswz));
        float4 a1v = *(const float4*)(abase + ((Xa + 16) ^ aswz));
        bf16x8 af;
        af[0]=f2bf(a0v.x); af[1]=f2bf(a0v.y); af[2]=f2bf(a0v.z); af[3]=f2bf(a0v.w);
        af[4]=f2bf(a1v.x); af[5]=f2bf(a1v.y); af[6]=f2bf(a1v.z); af[7]=f2bf(a1v.w);
        int xb = (ks * 64 + kb * 16) ^ bswz;
        bf16x8 b0 = *(const bf16x8*)(bbase + xb);
        bf16x8 b1 = *(const bf16x8*)(bbase + 16 * 256 + xb);
        bf16x8 b2 = *(const bf16x8*)(bbase + 32 * 256 + xb);
        bf16x8 b3 = *(const bf16x8*)(bbase + 48 * 256 + xb);
        c0 = __builtin_amdgcn_mfma_f32_16x16x32_bf16(af, b0, c0, 0, 0, 0);
        c1 = __builtin_amdgcn_mfma_f32_16x16x32_bf16(af, b1, c1, 0, 0, 0);
        c2 = __builtin_amdgcn_mfma_f32_16x16x32_bf16(af, b2, c2, 0, 0, 0);
        c3 = __builtin_amdgcn_mfma_f32_16x16x32_bf16(af, b3, c3, 0, 0, 0);
    }
}

__global__ __launch_bounds__(256) void gemm_lds_kernel(
        const float* __restrict__ Aimg, const float* __restrict__ Atxt,
        const short* __restrict__ Wti, const short* __restrict__ Wtt,
        const float* __restrict__ bimg, const float* __restrict__ btxt,
        unsigned* __restrict__ egob_items) {
    __shared__ __align__(16) float atile[2][64 * KCHUNK];   // 64 KB
    __shared__ __align__(16) short btile[2][64 * KCHUNK];   // 32 KB
    const int t = threadIdx.x;
    const int wave = t >> 6, lane = t & 63;
    const int col = lane & 15, kb = lane >> 4;
    const int row0 = blockIdx.x * 64;
    const int gmax = N_ITEMS - 1;

    // staging geometry (LDS dest linear: base + lane*16 per wave-call)
    const int s_arow  = 16 * wave + (lane >> 5);   // +2c per call
    const int s_axoff = (lane & 31) * 16;
    const int s_bcol  = 16 * wave + (lane >> 4);   // +4c per call
    const int s_bxoff = (lane & 15) * 16;

    auto stageA = [&](const float* A, int K, int k0, int bi) {
        #pragma unroll
        for (int c = 0; c < 8; ++c) {
            int r = s_arow + 2 * c;
            int gr = row0 + r; gr = gr > gmax ? gmax : gr;
            int sw = (r & 7) << 4;
            const char* src = (const char*)A + ((size_t)gr * K + k0) * 4 + (s_axoff ^ sw);
            char* dst = (char*)&atile[bi][0] + r * 512 + s_axoff;
            gload_lds16(src, dst);
        }
    };
    auto stageB = [&](const short* W, int K, int k0, int bi) {
        #pragma unroll
        for (int c = 0; c < 4; ++c) {
            int bc = s_bcol + 4 * c;
            int sw = (bc & 15) << 4;
            const char* src = (const char*)W + ((size_t)bc * K + k0) * 2 + (s_bxoff ^ sw);
            char* dst = (char*)&btile[bi][0] + bc * 256 + s_bxoff;
            gload_lds16(src, dst);
        }
    };

    f32x4 z = {0.f, 0.f, 0.f, 0.f};
    f32x4 ai0 = z, ai1 = z, ai2 = z, ai3 = z;
    f32x4 at0 = z, at1 = z, at2 = z, at3 = z;

    // ---- image phase: K=4096, 32 chunks
    stageA(Aimg, 4096, 0, 0); stageB(Wti, 4096, 0, 0);
    asm volatile("s_waitcnt vmcnt(0)" ::: "memory");
    __syncthreads();
    for (int ch = 0; ch < 32; ++ch) {
        int bi = ch & 1;
        if (ch + 1 < 32) {
            stageA(Aimg, 4096, (ch + 1) * KCHUNK, bi ^ 1);
            stageB(Wti, 4096, (ch + 1) * KCHUNK, bi ^ 1);
        }
        compute_chunk(&atile[bi][0], &btile[bi][0], wave, lane, ai0, ai1, ai2, ai3);
        asm volatile("s_waitcnt vmcnt(0)" ::: "memory");
        __syncthreads();
    }
    // ---- text phase: K=384, 3 chunks
    stageA(Atxt, 384, 0, 0); stageB(Wtt, 384, 0, 0);
    asm volatile("s_waitcnt vmcnt(0)" ::: "memory");
    __syncthreads();
    for (int ch = 0; ch < 3; ++ch) {
        int bi = ch & 1;
        if (ch + 1 < 3) {
            stageA(Atxt, 384, (ch + 1) * KCHUNK, bi ^ 1);
            stageB(Wtt, 384, (ch + 1) * KCHUNK, bi ^ 1);
        }
        compute_chunk(&atile[bi][0], &btile[bi][0], wave, lane, at0, at1, at2, at3);
        asm volatile("s_waitcnt vmcnt(0)" ::: "memory");
        __syncthreads();
    }

    // ---- bias + per-row L2 norm + packed mirror store
    float bi0 = bimg[ 0 + col], bi1 = bimg[16 + col], bi2 = bimg[32 + col], bi3 = bimg[48 + col];
    float bt0 = btxt[ 0 + col], bt1 = btxt[16 + col], bt2 = btxt[32 + col], bt3 = btxt[48 + col];
    #pragma unroll
    for (int i = 0; i < 4; ++i) {
        ai0[i] += bi0; ai1[i] += bi1; ai2[i] += bi2; ai3[i] += bi3;
        at0[i] += bt0; at1[i] += bt1; at2[i] += bt2; at3[i] += bt3;
    }
    #pragma unroll
    for (int i = 0; i < 4; ++i) {
        float ssi = ai0[i]*ai0[i] + ai1[i]*ai1[i] + ai2[i]*ai2[i] + ai3[i]*ai3[i];
        float sst = at0[i]*at0[i] + at1[i]*at1[i] + at2[i]*at2[i] + at3[i]*at3[i];
        #pragma unroll
        for (int off = 1; off < 16; off <<= 1) {
            ssi += __shfl_xor(ssi, off, 64);
            sst += __shfl_xor(sst, off, 64);
        }
        float rni = 1.0f / fmaxf(sqrtf(ssi), 1e-12f);
        float rnt = 1.0f / fmaxf(sqrtf(sst), 1e-12f);
        int r = row0 + 16 * wave + kb * 4 + i;
        if (r < N_ITEMS) {
            unsigned* ob = egob_items + (size_t)r * 64 + col;
            ob[ 0] = pack_bf2(ai0[i]*rni, at0[i]*rnt);
            ob[16] = pack_bf2(ai1[i]*rni, at1[i]*rnt);
            ob[32] = pack_bf2(ai2[i]*rni, at2[i]*rnt);
            ob[48] = pack_bf2(ai3[i]*rni, at3[i]*rnt);
        }
    }
}

// ---------------------------------------------------------------- per-row slot sort
// Bitonic sort of each row's ELL slots by col id (one 64-lane wave per row,
// 128-element network, 2 elems/lane). Duplicate edges carry identical (col,val),
// so the sorted sequence is unique -> bit-deterministic SpMM sums.

__global__ __launch_bounds__(256) void sort_kernel(const int* __restrict__ cnt,
                                                   int2* __restrict__ ell) {
    int row = blockIdx.x * 4 + (threadIdx.x >> 6);
    if (row >= N_TOTAL) return;
    int lane = threadIdx.x & 63;
    int deg = min(cnt[row], ELL_CAP);
    if (deg <= 1) return;
    int2* base = ell + (size_t)row * ELL_CAP;
    int2 e0 = (lane < deg)      ? base[lane]      : make_int2(0x7FFFFFFF, 0);
    int2 e1 = (lane + 64 < deg) ? base[lane + 64] : make_int2(0x7FFFFFFF, 0);
    #pragma unroll
    for (int k = 2; k <= 128; k <<= 1) {
        #pragma unroll
        for (int j = 64; j >= 1; j >>= 1) {
            if (j >= k) continue;
            if (j == 64) {
                if (e0.x > e1.x) { int2 tmp = e0; e0 = e1; e1 = tmp; }
            } else {
                int2 p0, p1;
                p0.x = __shfl_xor(e0.x, j, 64); p0.y = __shfl_xor(e0.y, j, 64);
                p1.x = __shfl_xor(e1.x, j, 64); p1.y = __shfl_xor(e1.y, j, 64);
                bool up0 = ((lane & k) == 0);
                bool up1 = (((lane + 64) & k) == 0);
                bool lo0 = ((lane & j) == 0);
                bool keepmin0 = (up0 == lo0);
                bool keepmin1 = (up1 == lo0);
                if (keepmin0 ? (e0.x > p0.x) : (e0.x < p0.x)) e0 = p0;
                if (keepmin1 ? (e1.x > p1.x) : (e1.x < p1.x)) e1 = p1;
            }
        }
    }
    if (lane < deg)      base[lane]      = e0;
    if (lane + 64 < deg) base[lane + 64] = e1;
}

// ---------------------------------------------------------------- SpMM layer (bf16 state)

__global__ __launch_bounds__(256) void spmm_kernel(
        const int* __restrict__ cnt, const int2* __restrict__ ell,
        const unsigned* __restrict__ xb,
        float* __restrict__ out32, unsigned* __restrict__ outb) {
    int row = blockIdx.x * 4 + (threadIdx.x >> 6);
    if (row >= N_TOTAL) return;
    int lane = threadIdx.x & 63;
    unsigned sw = xb[(size_t)row * 64 + lane];
    float2 acc;
    acc.x = ALPHA_F * bf_lo(sw);
    acc.y = ALPHA_F * bf_hi(sw);
    int deg = min(cnt[row], ELL_CAP);
    const int2* base = ell + (size_t)row * ELL_CAP;
    int i = 0;
    for (; i + 8 <= deg; i += 8) {
        int4 p0 = *reinterpret_cast<const int4*>(base + i);
        int4 p1 = *reinterpret_cast<const int4*>(base + i + 2);
        int4 p2 = *reinterpret_cast<const int4*>(base + i + 4);
        int4 p3 = *reinterpret_cast<const int4*>(base + i + 6);
        unsigned g0 = xb[(size_t)p0.x * 64 + lane];
        unsigned g1 = xb[(size_t)p0.z * 64 + lane];
        unsigned g2 = xb[(size_t)p1.x * 64 + lane];
        unsigned g3 = xb[(size_t)p1.z * 64 + lane];
        unsigned g4 = xb[(size_t)p2.x * 64 + lane];
        unsigned g5 = xb[(size_t)p2.z * 64 + lane];
        unsigned g6 = xb[(size_t)p3.x * 64 + lane];
        unsigned g7 = xb[(size_t)p3.z * 64 + lane];
        float v0 = __int_as_float(p0.y), v1 = __int_as_float(p0.w);
        float v2 = __int_as_float(p1.y), v3 = __int_as_float(p1.w);
        float v4 = __int_as_float(p2.y), v5 = __int_as_float(p2.w);
        float v6 = __int_as_float(p3.y), v7 = __int_as_float(p3.w);
        acc.x = fmaf(v0, bf_lo(g0), acc.x); acc.y = fmaf(v0, bf_hi(g0), acc.y);
        acc.x = fmaf(v1, bf_lo(g1), acc.x); acc.y = fmaf(v1, bf_hi(g1), acc.y);
        acc.x = fmaf(v2, bf_lo(g2), acc.x); acc.y = fmaf(v2, bf_hi(g2), acc.y);
        acc.x = fmaf(v3, bf_lo(g3), acc.x); acc.y = fmaf(v3, bf_hi(g3), acc.y);
        acc.x = fmaf(v4, bf_lo(g4), acc.x); acc.y = fmaf(v4, bf_hi(g4), acc.y);
        acc.x = fmaf(v5, bf_lo(g5), acc.x); acc.y = fmaf(v5, bf_hi(g5), acc.y);
        acc.x = fmaf(v6, bf_lo(g6), acc.x); acc.y = fmaf(v6, bf_hi(g6), acc.y);
        acc.x = fmaf(v7, bf_lo(g7), acc.x); acc.y = fmaf(v7, bf_hi(g7), acc.y);
    }
    for (; i < deg; ++i) {
        int2 c = base[i];
        float v = __int_as_float(c.y);
        unsigned g = xb[(size_t)c.x * 64 + lane];
        acc.x = fmaf(v, bf_lo(g), acc.x);
        acc.y = fmaf(v, bf_hi(g), acc.y);
    }
    if (out32) {
        out32[(size_t)row * 128 + lane] = acc.x;
        out32[(size_t)row * 128 + 64 + lane] = acc.y;
    }
    if (outb)
        outb[(size_t)row * 64 + lane] = pack_bf2(acc.x, acc.y);
}

// ---------------------------------------------------------------- launch

extern "C" void kernel_launch(void* const* d_in, const int* in_sizes, int n_in,
                              void* d_out, int out_size, void* d_ws, size_t ws_size,
                              hipStream_t stream) {
    const float* image_feats = (const float*)d_in[0];
    const float* text_feats  = (const float*)d_in[1];
    const float* image_pref  = (const float*)d_in[2];
    const float* text_pref   = (const float*)d_in[3];
    const float* W_img       = (const float*)d_in[4];
    const float* b_img       = (const float*)d_in[5];
    const float* W_txt       = (const float*)d_in[6];
    const float* b_txt       = (const float*)d_in[7];
    const float* adj_vals    = (const float*)d_in[8];
    const int*   adj_rows    = (const int*)d_in[9];
    const int*   adj_cols    = (const int*)d_in[10];

    float* out = (float*)d_out;                          // [150000*128]

    char* ws = (char*)d_ws;
    size_t off = 0;
    auto alloc = [&](size_t bytes) { char* p = ws + off; off += (bytes + 255) & ~size_t(255); return p; };
    int*      cnt    = (int*)     alloc(N_TOTAL * sizeof(int));
    int2*     ell    = (int2*)    alloc((size_t)N_TOTAL * ELL_CAP * sizeof(int2));
    unsigned* m0     = (unsigned*)alloc((size_t)N_TOTAL * 64 * sizeof(unsigned));
    unsigned* m1     = (unsigned*)alloc((size_t)N_TOTAL * 64 * sizeof(unsigned));
    short*    Wt_img = (short*)   alloc((size_t)64 * 4096 * sizeof(short));
    short*    Wt_txt = (short*)   alloc((size_t)64 * 384 * sizeof(short));
    (void)ws_size; (void)out_size; (void)n_in; (void)in_sizes;

    // --- prep: zero cnt + bf16 W transposes ---
    prep_kernel<<<512, 256, 0, stream>>>(W_img, W_txt, cnt, Wt_img, Wt_txt);

    // --- scatter + user-pref copy ---
    scat_copy_kernel<<<C_COPY + C_SCAT, 256, 0, stream>>>(
        adj_rows, adj_cols, adj_vals, cnt, ell, image_pref, text_pref, m0);

    // --- item GEMM + l2norm -> bf16 mirror item rows (async-LDS pipeline) ---
    unsigned* m0_items = m0 + (size_t)N_USERS * 64;
    gemm_lds_kernel<<<(N_ITEMS + 63) / 64, 256, 0, stream>>>(
        image_feats, text_feats, Wt_img, Wt_txt, b_img, b_txt, m0_items);

    // --- canonicalize ELL slot order (bit-determinism across calls) ---
    const int ROW_GRID = (N_TOTAL + 3) / 4;
    sort_kernel<<<ROW_GRID, 256, 0, stream>>>(cnt, ell);

    // --- 3 propagation layers (bf16 state; final layer writes f32 d_out) ---
    spmm_kernel<<<ROW_GRID, 256, 0, stream>>>(cnt, ell, m0, nullptr, m1);
    spmm_kernel<<<ROW_GRID, 256, 0, stream>>>(cnt, ell, m1, nullptr, m0);
    spmm_kernel<<<ROW_GRID, 256, 0, stream>>>(cnt, ell, m0, out, nullptr);
}

// Round 10
// 995.665 us; speedup vs baseline: 1.1859x; 1.1455x over previous
//
#include <hip/hip_runtime.h>
#include <hip/hip_bf16.h>

#define N_USERS 100000
#define N_ITEMS 50000
#define N_TOTAL 150000
#define NNZ     4000000
#define ALPHA_F 0.8f
#define ELL_CAP 128   // max row degree ~70 (users ~Poisson(20), items ~Poisson(40))

#define G_GEMM 782    // (N_ITEMS+63)/64
#define G_COPY 256
#define G_SCAT 1024
#define NC_IMG 64     // 4096/64
#define NC_ALL 70     // + 384/64

typedef __attribute__((ext_vector_type(8))) short bf16x8;
typedef __attribute__((ext_vector_type(4))) float f32x4;

static __device__ __forceinline__ short f2bf(float f) {
    unsigned u = __builtin_bit_cast(unsigned, f);
    unsigned r = (u + 0x7fff + ((u >> 16) & 1)) >> 16;   // RTNE
    return (short)r;
}
static __device__ __forceinline__ unsigned pack_bf2(float a, float b) {
    return (unsigned)(unsigned short)f2bf(a) | ((unsigned)(unsigned short)f2bf(b) << 16);
}
static __device__ __forceinline__ float bf_lo(unsigned u) { return __uint_as_float(u << 16); }
static __device__ __forceinline__ float bf_hi(unsigned u) { return __uint_as_float(u & 0xFFFF0000u); }

static __device__ __forceinline__ void gload_lds16(const void* src, void* dst) {
    __builtin_amdgcn_global_load_lds(
        (const __attribute__((address_space(1))) unsigned*)src,
        (__attribute__((address_space(3))) unsigned*)dst, 16, 0, 0);
}

// ---------------------------------------------------------------- prep: zero cnt + W transposes

__global__ __launch_bounds__(256) void prep_kernel(const float* __restrict__ Wimg,
                                                   const float* __restrict__ Wtxt,
                                                   int* __restrict__ cnt,
                                                   short* __restrict__ Wti,
                                                   short* __restrict__ Wtt) {
    const int T0 = N_TOTAL;
    const int T1 = T0 + 4096 * 64;
    const int T2 = T1 + 384 * 64;
    int i = blockIdx.x * 256 + threadIdx.x;
    int stride = gridDim.x * 256;
    for (; i < T2; i += stride) {
        if (i < T0) {
            cnt[i] = 0;
        } else if (i < T1) {
            int idx = i - T0; int k = idx >> 6, n = idx & 63;
            Wti[(size_t)n * 4096 + k] = f2bf(Wimg[(size_t)k * 64 + n]);
        } else {
            int idx = i - T1; int k = idx >> 6, n = idx & 63;
            Wtt[(size_t)n * 384 + k] = f2bf(Wtxt[(size_t)k * 64 + n]);
        }
    }
}

// ---------------------------------------------------------------- compute one 64x64-K chunk
// A frag: lane l = A[16w + (l&15)][k0 + (l>>4)*8 + j]; LDS row stride 256B, XOR (row&7)<<4.
// B frag: lane l = Wt[col + 16j][k0 + (l>>4)*8 + .]; LDS col stride 128B, XOR (col&7)<<4.

static __device__ __forceinline__ void compute_chunk(
        const float* at, const short* bt, int wave, int lane,
        f32x4& c0, f32x4& c1, f32x4& c2, f32x4& c3) {
    const int col = lane & 15, kb = lane >> 4;
    const int arow = 16 * wave + col;
    const char* abase = (const char*)at + arow * 256;
    const int aswz = (arow & 7) << 4;
    const int bswz = (col & 7) << 4;
    const char* bb = (const char*)bt;
    #pragma unroll
    for (int ks = 0; ks < 2; ++ks) {
        int Xa = ks * 128 + kb * 32;
        float4 a0v = *(const float4*)(abase + ((Xa)      ^ aswz));
        float4 a1v = *(const float4*)(abase + ((Xa + 16) ^ aswz));
        bf16x8 af;
        af[0]=f2bf(a0v.x); af[1]=f2bf(a0v.y); af[2]=f2bf(a0v.z); af[3]=f2bf(a0v.w);
        af[4]=f2bf(a1v.x); af[5]=f2bf(a1v.y); af[6]=f2bf(a1v.z); af[7]=f2bf(a1v.w);
        int xb = (ks * 64 + kb * 16) ^ bswz;
        bf16x8 b0 = *(const bf16x8*)(bb + (col +  0) * 128 + xb);
        bf16x8 b1 = *(const bf16x8*)(bb + (col + 16) * 128 + xb);
        bf16x8 b2 = *(const bf16x8*)(bb + (col + 32) * 128 + xb);
        bf16x8 b3 = *(const bf16x8*)(bb + (col + 48) * 128 + xb);
        c0 = __builtin_amdgcn_mfma_f32_16x16x32_bf16(af, b0, c0, 0, 0, 0);
        c1 = __builtin_amdgcn_mfma_f32_16x16x32_bf16(af, b1, c1, 0, 0, 0);
        c2 = __builtin_amdgcn_mfma_f32_16x16x32_bf16(af, b2, c2, 0, 0, 0);
        c3 = __builtin_amdgcn_mfma_f32_16x16x32_bf16(af, b3, c3, 0, 0, 0);
    }
}

// ---------------------------------------------------------------- mega kernel
// [0, G_GEMM): item GEMM (48KB LDS dbuf, counted-vmcnt pipeline, 3 blocks/CU)
// [G_GEMM, +G_COPY): user pref -> bf16 mirror
// [.., +G_SCAT): ELL scatter (atomic slot; canonicalized by in-spmm1 sort)

__global__ __launch_bounds__(256) void mega_kernel(
        const float* __restrict__ Aimg, const float* __restrict__ Atxt,
        const short* __restrict__ Wti, const short* __restrict__ Wtt,
        const float* __restrict__ bimg, const float* __restrict__ btxt,
        unsigned* __restrict__ egob,
        const int* __restrict__ rows, const int* __restrict__ cols,
        const float* __restrict__ vals, int* __restrict__ cnt, int2* __restrict__ ell,
        const float* __restrict__ img_pref, const float* __restrict__ txt_pref) {
    __shared__ __align__(16) float atile[2][64 * 64];   // 32 KB
    __shared__ __align__(16) short btile[2][64 * 64];   // 16 KB
    int b = blockIdx.x;
    int t = threadIdx.x;
    int wave = t >> 6, lane = t & 63;
    if (b < G_GEMM) {
        const int row0 = b * 64;
        const int gmax = N_ITEMS - 1;
        const int col = lane & 15, kb = lane >> 4;

        // A: call c covers rows g*4..g*4+3 (g = c*4+wave); lane -> row g*4+(l>>4), slot l&15
        auto stageA = [&](const float* A, int K, int k0, int bi) {
            #pragma unroll
            for (int c = 0; c < 4; ++c) {
                int g = c * 4 + wave;
                int r = g * 4 + (lane >> 4);
                int gr = row0 + r; gr = gr > gmax ? gmax : gr;
                int boff = ((lane & 15) * 16) ^ ((r & 7) << 4);
                const char* src = (const char*)A + ((size_t)gr * K + k0) * 4 + boff;
                char* dst = (char*)&atile[bi][0] + g * 1024 + lane * 16;
                gload_lds16(src, dst);
            }
        };
        // B: call c covers cols g*8..g*8+7; lane -> col g*8+(l>>3), slot l&7
        auto stageB = [&](const short* W, int K, int k0, int bi) {
            #pragma unroll
            for (int c = 0; c < 2; ++c) {
                int g = c * 4 + wave;
                int bc = g * 8 + (lane >> 3);
                int boff = ((lane & 7) * 16) ^ ((bc & 7) << 4);
                const char* src = (const char*)W + ((size_t)bc * K + k0) * 2 + boff;
                char* dst = (char*)&btile[bi][0] + g * 1024 + lane * 16;
                gload_lds16(src, dst);
            }
        };
        auto stage = [&](int ci, int bi) {
            if (ci < NC_IMG) { stageA(Aimg, 4096, ci * 64, bi); stageB(Wti, 4096, ci * 64, bi); }
            else { stageA(Atxt, 384, (ci - NC_IMG) * 64, bi); stageB(Wtt, 384, (ci - NC_IMG) * 64, bi); }
        };

        f32x4 z = {0.f,0.f,0.f,0.f};
        f32x4 ai0 = z, ai1 = z, ai2 = z, ai3 = z;
        f32x4 at0 = z, at1 = z, at2 = z, at3 = z;

        stage(0, 0);
        for (int ci = 0; ci < NC_ALL; ++ci) {
            int bi = ci & 1;
            if (ci + 1 < NC_ALL) {
                stage(ci + 1, bi ^ 1);
                asm volatile("s_waitcnt vmcnt(6)" ::: "memory");   // my stage(ci) done; prefetch in flight
            } else {
                asm volatile("s_waitcnt vmcnt(0)" ::: "memory");
            }
            __builtin_amdgcn_s_barrier();
            __builtin_amdgcn_sched_barrier(0);
            if (ci < NC_IMG) compute_chunk(&atile[bi][0], &btile[bi][0], wave, lane, ai0, ai1, ai2, ai3);
            else             compute_chunk(&atile[bi][0], &btile[bi][0], wave, lane, at0, at1, at2, at3);
            asm volatile("" ::: "memory");
            __builtin_amdgcn_s_barrier();                           // all done reading buf bi
            __builtin_amdgcn_sched_barrier(0);
        }

        float bi0 = bimg[ 0 + col], bi1 = bimg[16 + col], bi2 = bimg[32 + col], bi3 = bimg[48 + col];
        float bt0 = btxt[ 0 + col], bt1 = btxt[16 + col], bt2 = btxt[32 + col], bt3 = btxt[48 + col];
        #pragma unroll
        for (int i = 0; i < 4; ++i) {
            ai0[i] += bi0; ai1[i] += bi1; ai2[i] += bi2; ai3[i] += bi3;
            at0[i] += bt0; at1[i] += bt1; at2[i] += bt2; at3[i] += bt3;
        }
        unsigned* egob_items = egob + (size_t)N_USERS * 64;
        #pragma unroll
        for (int i = 0; i < 4; ++i) {
            float ssi = ai0[i]*ai0[i] + ai1[i]*ai1[i] + ai2[i]*ai2[i] + ai3[i]*ai3[i];
            float sst = at0[i]*at0[i] + at1[i]*at1[i] + at2[i]*at2[i] + at3[i]*at3[i];
            #pragma unroll
            for (int off = 1; off < 16; off <<= 1) {
                ssi += __shfl_xor(ssi, off, 64);
                sst += __shfl_xor(sst, off, 64);
            }
            float rni = 1.0f / fmaxf(sqrtf(ssi), 1e-12f);
            float rnt = 1.0f / fmaxf(sqrtf(sst), 1e-12f);
            int r = row0 + 16 * wave + kb * 4 + i;
            if (r < N_ITEMS) {
                unsigned* ob = egob_items + (size_t)r * 64 + col;
                ob[ 0] = pack_bf2(ai0[i]*rni, at0[i]*rnt);
                ob[16] = pack_bf2(ai1[i]*rni, at1[i]*rnt);
                ob[32] = pack_bf2(ai2[i]*rni, at2[i]*rnt);
                ob[48] = pack_bf2(ai3[i]*rni, at3[i]*rnt);
            }
        }
    } else if (b < G_GEMM + G_COPY) {
        int idx = (b - G_GEMM) * 256 + t;
        int stride = G_COPY * 256;
        for (; idx < N_USERS * 16; idx += stride) {
            int row = idx >> 4, w4 = (idx & 15) << 2;
            float4 iv = *reinterpret_cast<const float4*>(&img_pref[(size_t)row * 64 + w4]);
            float4 tv = *reinterpret_cast<const float4*>(&txt_pref[(size_t)row * 64 + w4]);
            uint4 m;
            m.x = pack_bf2(iv.x, tv.x); m.y = pack_bf2(iv.y, tv.y);
            m.z = pack_bf2(iv.z, tv.z); m.w = pack_bf2(iv.w, tv.w);
            *reinterpret_cast<uint4*>(&egob[(size_t)row * 64 + w4]) = m;
        }
    } else {
        int i = (b - G_GEMM - G_COPY) * 256 + t;
        int stride = G_SCAT * 256;
        for (; i < NNZ; i += stride) {
            int r = rows[i];
            int p = atomicAdd(&cnt[r], 1);
            if (p < ELL_CAP)
                ell[(size_t)r * ELL_CAP + p] = make_int2(cols[i], __float_as_int(vals[i]));
        }
    }
}

// ---------------------------------------------------------------- SpMM layer 1 + fused sort
// Wave per row: load 128 slots (2/lane), bitonic-sort by col (canonical, deterministic),
// write back for layers 2-3, stash in LDS, then gather-accumulate in sorted order.

__global__ __launch_bounds__(256) void spmm_sort_kernel(
        const int* __restrict__ cnt, int2* __restrict__ ell,
        const unsigned* __restrict__ xb, unsigned* __restrict__ outb) {
    __shared__ __align__(16) int2 srt[4][ELL_CAP];
    int wid = threadIdx.x >> 6, lane = threadIdx.x & 63;
    int row = blockIdx.x * 4 + wid;
    bool valid = row < N_TOTAL;
    int deg = 0;
    int2* base = nullptr;
    int2 e0 = make_int2(0x7FFFFFFF, 0), e1 = e0;
    if (valid) {
        deg = min(cnt[row], ELL_CAP);
        base = ell + (size_t)row * ELL_CAP;
        if (lane < deg)      e0 = base[lane];
        if (lane + 64 < deg) e1 = base[lane + 64];
    }
    #pragma unroll
    for (int k = 2; k <= 128; k <<= 1) {
        #pragma unroll
        for (int j = 64; j >= 1; j >>= 1) {
            if (j >= k) continue;
            if (j == 64) {
                if (e0.x > e1.x) { int2 tmp = e0; e0 = e1; e1 = tmp; }
            } else {
                int2 p0, p1;
                p0.x = __shfl_xor(e0.x, j, 64); p0.y = __shfl_xor(e0.y, j, 64);
                p1.x = __shfl_xor(e1.x, j, 64); p1.y = __shfl_xor(e1.y, j, 64);
                bool up0 = ((lane & k) == 0);
                bool up1 = (((lane + 64) & k) == 0);
                bool lo0 = ((lane & j) == 0);
                bool keepmin0 = (up0 == lo0);
                bool keepmin1 = (up1 == lo0);
                if (keepmin0 ? (e0.x > p0.x) : (e0.x < p0.x)) e0 = p0;
                if (keepmin1 ? (e1.x > p1.x) : (e1.x < p1.x)) e1 = p1;
            }
        }
    }
    if (valid) {
        if (lane < deg)      base[lane]      = e0;   // canonical order for layers 2-3
        if (lane + 64 < deg) base[lane + 64] = e1;
    }
    srt[wid][lane] = e0;
    srt[wid][lane + 64] = e1;
    __syncthreads();
    if (!valid) return;
    unsigned sw = xb[(size_t)row * 64 + lane];
    float2 acc;
    acc.x = ALPHA_F * bf_lo(sw);
    acc.y = ALPHA_F * bf_hi(sw);
    const int2* s = srt[wid];
    int i = 0;
    for (; i + 8 <= deg; i += 8) {
        int4 p0 = *reinterpret_cast<const int4*>(s + i);
        int4 p1 = *reinterpret_cast<const int4*>(s + i + 2);
        int4 p2 = *reinterpret_cast<const int4*>(s + i + 4);
        int4 p3 = *reinterpret_cast<const int4*>(s + i + 6);
        unsigned g0 = xb[(size_t)p0.x * 64 + lane];
        unsigned g1 = xb[(size_t)p0.z * 64 + lane];
        unsigned g2 = xb[(size_t)p1.x * 64 + lane];
        unsigned g3 = xb[(size_t)p1.z * 64 + lane];
        unsigned g4 = xb[(size_t)p2.x * 64 + lane];
        unsigned g5 = xb[(size_t)p2.z * 64 + lane];
        unsigned g6 = xb[(size_t)p3.x * 64 + lane];
        unsigned g7 = xb[(size_t)p3.z * 64 + lane];
        float v0 = __int_as_float(p0.y), v1 = __int_as_float(p0.w);
        float v2 = __int_as_float(p1.y), v3 = __int_as_float(p1.w);
        float v4 = __int_as_float(p2.y), v5 = __int_as_float(p2.w);
        float v6 = __int_as_float(p3.y), v7 = __int_as_float(p3.w);
        acc.x = fmaf(v0, bf_lo(g0), acc.x); acc.y = fmaf(v0, bf_hi(g0), acc.y);
        acc.x = fmaf(v1, bf_lo(g1), acc.x); acc.y = fmaf(v1, bf_hi(g1), acc.y);
        acc.x = fmaf(v2, bf_lo(g2), acc.x); acc.y = fmaf(v2, bf_hi(g2), acc.y);
        acc.x = fmaf(v3, bf_lo(g3), acc.x); acc.y = fmaf(v3, bf_hi(g3), acc.y);
        acc.x = fmaf(v4, bf_lo(g4), acc.x); acc.y = fmaf(v4, bf_hi(g4), acc.y);
        acc.x = fmaf(v5, bf_lo(g5), acc.x); acc.y = fmaf(v5, bf_hi(g5), acc.y);
        acc.x = fmaf(v6, bf_lo(g6), acc.x); acc.y = fmaf(v6, bf_hi(g6), acc.y);
        acc.x = fmaf(v7, bf_lo(g7), acc.x); acc.y = fmaf(v7, bf_hi(g7), acc.y);
    }
    for (; i < deg; ++i) {
        int2 c = s[i];
        float v = __int_as_float(c.y);
        unsigned g = xb[(size_t)c.x * 64 + lane];
        acc.x = fmaf(v, bf_lo(g), acc.x);
        acc.y = fmaf(v, bf_hi(g), acc.y);
    }
    outb[(size_t)row * 64 + lane] = pack_bf2(acc.x, acc.y);
}

// ---------------------------------------------------------------- SpMM layers 2-3 (canonical ELL)

__global__ __launch_bounds__(256) void spmm_kernel(
        const int* __restrict__ cnt, const int2* __restrict__ ell,
        const unsigned* __restrict__ xb,
        float* __restrict__ out32, unsigned* __restrict__ outb) {
    int row = blockIdx.x * 4 + (threadIdx.x >> 6);
    if (row >= N_TOTAL) return;
    int lane = threadIdx.x & 63;
    unsigned sw = xb[(size_t)row * 64 + lane];
    float2 acc;
    acc.x = ALPHA_F * bf_lo(sw);
    acc.y = ALPHA_F * bf_hi(sw);
    int deg = min(cnt[row], ELL_CAP);
    const int2* base = ell + (size_t)row * ELL_CAP;
    int i = 0;
    for (; i + 8 <= deg; i += 8) {
        int4 p0 = *reinterpret_cast<const int4*>(base + i);
        int4 p1 = *reinterpret_cast<const int4*>(base + i + 2);
        int4 p2 = *reinterpret_cast<const int4*>(base + i + 4);
        int4 p3 = *reinterpret_cast<const int4*>(base + i + 6);
        unsigned g0 = xb[(size_t)p0.x * 64 + lane];
        unsigned g1 = xb[(size_t)p0.z * 64 + lane];
        unsigned g2 = xb[(size_t)p1.x * 64 + lane];
        unsigned g3 = xb[(size_t)p1.z * 64 + lane];
        unsigned g4 = xb[(size_t)p2.x * 64 + lane];
        unsigned g5 = xb[(size_t)p2.z * 64 + lane];
        unsigned g6 = xb[(size_t)p3.x * 64 + lane];
        unsigned g7 = xb[(size_t)p3.z * 64 + lane];
        float v0 = __int_as_float(p0.y), v1 = __int_as_float(p0.w);
        float v2 = __int_as_float(p1.y), v3 = __int_as_float(p1.w);
        float v4 = __int_as_float(p2.y), v5 = __int_as_float(p2.w);
        float v6 = __int_as_float(p3.y), v7 = __int_as_float(p3.w);
        acc.x = fmaf(v0, bf_lo(g0), acc.x); acc.y = fmaf(v0, bf_hi(g0), acc.y);
        acc.x = fmaf(v1, bf_lo(g1), acc.x); acc.y = fmaf(v1, bf_hi(g1), acc.y);
        acc.x = fmaf(v2, bf_lo(g2), acc.x); acc.y = fmaf(v2, bf_hi(g2), acc.y);
        acc.x = fmaf(v3, bf_lo(g3), acc.x); acc.y = fmaf(v3, bf_hi(g3), acc.y);
        acc.x = fmaf(v4, bf_lo(g4), acc.x); acc.y = fmaf(v4, bf_hi(g4), acc.y);
        acc.x = fmaf(v5, bf_lo(g5), acc.x); acc.y = fmaf(v5, bf_hi(g5), acc.y);
        acc.x = fmaf(v6, bf_lo(g6), acc.x); acc.y = fmaf(v6, bf_hi(g6), acc.y);
        acc.x = fmaf(v7, bf_lo(g7), acc.x); acc.y = fmaf(v7, bf_hi(g7), acc.y);
    }
    for (; i < deg; ++i) {
        int2 c = base[i];
        float v = __int_as_float(c.y);
        unsigned g = xb[(size_t)c.x * 64 + lane];
        acc.x = fmaf(v, bf_lo(g), acc.x);
        acc.y = fmaf(v, bf_hi(g), acc.y);
    }
    if (out32) {
        out32[(size_t)row * 128 + lane] = acc.x;
        out32[(size_t)row * 128 + 64 + lane] = acc.y;
    }
    if (outb)
        outb[(size_t)row * 64 + lane] = pack_bf2(acc.x, acc.y);
}

// ---------------------------------------------------------------- launch

extern "C" void kernel_launch(void* const* d_in, const int* in_sizes, int n_in,
                              void* d_out, int out_size, void* d_ws, size_t ws_size,
                              hipStream_t stream) {
    const float* image_feats = (const float*)d_in[0];
    const float* text_feats  = (const float*)d_in[1];
    const float* image_pref  = (const float*)d_in[2];
    const float* text_pref   = (const float*)d_in[3];
    const float* W_img       = (const float*)d_in[4];
    const float* b_img       = (const float*)d_in[5];
    const float* W_txt       = (const float*)d_in[6];
    const float* b_txt       = (const float*)d_in[7];
    const float* adj_vals    = (const float*)d_in[8];
    const int*   adj_rows    = (const int*)d_in[9];
    const int*   adj_cols    = (const int*)d_in[10];

    float* out = (float*)d_out;                          // [150000*128]

    char* ws = (char*)d_ws;
    size_t off = 0;
    auto alloc = [&](size_t bytes) { char* p = ws + off; off += (bytes + 255) & ~size_t(255); return p; };
    int*      cnt    = (int*)     alloc(N_TOTAL * sizeof(int));
    int2*     ell    = (int2*)    alloc((size_t)N_TOTAL * ELL_CAP * sizeof(int2));
    unsigned* m0     = (unsigned*)alloc((size_t)N_TOTAL * 64 * sizeof(unsigned));
    unsigned* m1     = (unsigned*)alloc((size_t)N_TOTAL * 64 * sizeof(unsigned));
    short*    Wt_img = (short*)   alloc((size_t)64 * 4096 * sizeof(short));
    short*    Wt_txt = (short*)   alloc((size_t)64 * 384 * sizeof(short));
    (void)ws_size; (void)out_size; (void)n_in; (void)in_sizes;

    // --- prep: zero cnt + bf16 W transposes ---
    prep_kernel<<<512, 256, 0, stream>>>(W_img, W_txt, cnt, Wt_img, Wt_txt);

    // --- mega: GEMM+norm -> m0 || user pref -> m0 || ELL scatter ---
    mega_kernel<<<G_GEMM + G_COPY + G_SCAT, 256, 0, stream>>>(
        image_feats, text_feats, Wt_img, Wt_txt, b_img, b_txt, m0,
        adj_rows, adj_cols, adj_vals, cnt, ell, image_pref, text_pref);

    // --- layer 1 (+ canonical in-kernel sort), then layers 2-3 ---
    const int ROW_GRID = (N_TOTAL + 3) / 4;
    spmm_sort_kernel<<<ROW_GRID, 256, 0, stream>>>(cnt, ell, m0, m1);
    spmm_kernel<<<ROW_GRID, 256, 0, stream>>>(cnt, ell, m1, nullptr, m0);
    spmm_kernel<<<ROW_GRID, 256, 0, stream>>>(cnt, ell, m0, out, nullptr);
}

// Round 11
// 976.268 us; speedup vs baseline: 1.2095x; 1.0199x over previous
//
#include <hip/hip_runtime.h>
#include <hip/hip_bf16.h>

#define N_USERS 100000
#define N_ITEMS 50000
#define N_TOTAL 150000
#define NNZ     4000000
#define ALPHA_F 0.8f
#define ELL_CAP 128

#define G_SCAT 256
#define G_COPY 128
#define G_PRE  (G_SCAT + G_COPY)
#define G_GEMM 3125           // N_ITEMS / 16 exactly

typedef __attribute__((ext_vector_type(8))) short bf16x8;
typedef __attribute__((ext_vector_type(4))) float f32x4;

static __device__ __forceinline__ short f2bf(float f) {
    unsigned u = __builtin_bit_cast(unsigned, f);
    unsigned r = (u + 0x7fff + ((u >> 16) & 1)) >> 16;   // RTNE
    return (short)r;
}
static __device__ __forceinline__ unsigned pack_bf2(float a, float b) {
    return (unsigned)(unsigned short)f2bf(a) | ((unsigned)(unsigned short)f2bf(b) << 16);
}
static __device__ __forceinline__ float bf_lo(unsigned u) { return __uint_as_float(u << 16); }
static __device__ __forceinline__ float bf_hi(unsigned u) { return __uint_as_float(u & 0xFFFF0000u); }

static __device__ __forceinline__ void gload_lds16(const void* src, void* dst) {
    __builtin_amdgcn_global_load_lds(
        (const __attribute__((address_space(1))) unsigned*)src,
        (__attribute__((address_space(3))) unsigned*)dst, 16, 0, 0);
}

// ---------------------------------------------------------------- prep: zero cnt + W transposes

__global__ __launch_bounds__(256) void prep_kernel(const float* __restrict__ Wimg,
                                                   const float* __restrict__ Wtxt,
                                                   int* __restrict__ cnt,
                                                   short* __restrict__ Wti,
                                                   short* __restrict__ Wtt) {
    const int T0 = N_TOTAL;
    const int T1 = T0 + 4096 * 64;
    const int T2 = T1 + 384 * 64;
    int i = blockIdx.x * 256 + threadIdx.x;
    int stride = gridDim.x * 256;
    for (; i < T2; i += stride) {
        if (i < T0) {
            cnt[i] = 0;
        } else if (i < T1) {
            int idx = i - T0; int k = idx >> 6, n = idx & 63;
            Wti[(size_t)n * 4096 + k] = f2bf(Wimg[(size_t)k * 64 + n]);
        } else {
            int idx = i - T1; int k = idx >> 6, n = idx & 63;
            Wtt[(size_t)n * 384 + k] = f2bf(Wtxt[(size_t)k * 64 + n]);
        }
    }
}

// ---------------------------------------------------------------- mega kernel
// [0, G_SCAT):      ELL scatter  (co-resident with GEMM from dispatch start)
// [G_SCAT, G_PRE):  user pref -> bf16 mirror
// [G_PRE, ...):     item GEMM: 16 rows/block, K-chunk 256 (1KB/row contiguous),
//                   A staged via global_load_lds (32KB dbuf), B direct from L2.

__global__ __launch_bounds__(256, 4) void mega_kernel(
        const float* __restrict__ Aimg, const float* __restrict__ Atxt,
        const short* __restrict__ Wti, const short* __restrict__ Wtt,
        const float* __restrict__ bimg, const float* __restrict__ btxt,
        unsigned* __restrict__ egob,
        const int* __restrict__ rows, const int* __restrict__ cols,
        const float* __restrict__ vals, int* __restrict__ cnt, int2* __restrict__ ell,
        const float* __restrict__ img_pref, const float* __restrict__ txt_pref) {
    __shared__ __align__(16) char atile[32768];   // two 16KB halves
    int b = blockIdx.x;
    int t = threadIdx.x;
    int wave = t >> 6, lane = t & 63;

    if (b < G_SCAT) {
        int i = b * 256 + t;
        int stride = G_SCAT * 256;
        for (; i < NNZ; i += stride) {
            int r = rows[i];
            int p = atomicAdd(&cnt[r], 1);
            if (p < ELL_CAP)
                ell[(size_t)r * ELL_CAP + p] = make_int2(cols[i], __float_as_int(vals[i]));
        }
        return;
    }
    if (b < G_PRE) {
        int idx = (b - G_SCAT) * 256 + t;
        int stride = G_COPY * 256;
        for (; idx < N_USERS * 16; idx += stride) {
            int row = idx >> 4, w4 = (idx & 15) << 2;
            float4 iv = *reinterpret_cast<const float4*>(&img_pref[(size_t)row * 64 + w4]);
            float4 tv = *reinterpret_cast<const float4*>(&txt_pref[(size_t)row * 64 + w4]);
            uint4 m;
            m.x = pack_bf2(iv.x, tv.x); m.y = pack_bf2(iv.y, tv.y);
            m.z = pack_bf2(iv.z, tv.z); m.w = pack_bf2(iv.w, tv.w);
            *reinterpret_cast<uint4*>(&egob[(size_t)row * 64 + w4]) = m;
        }
        return;
    }

    // ---------------- GEMM ----------------
    const int blk = b - G_PRE;
    const int row0 = blk * 16;
    const int col = lane & 15, kb = lane >> 4;

    // stage one 16x256 f32 chunk of Aimg (4 insts/wave, 1KB contiguous per row)
    auto stage_img = [&](int ci, int bi) {
        #pragma unroll
        for (int j = 0; j < 4; ++j) {
            int r = wave * 4 + j;
            int swz = (r & 7) << 4;
            const char* src = (const char*)Aimg + (size_t)(row0 + r) * 16384
                              + ci * 1024 + ((lane * 16) ^ swz);
            char* dst = (char*)atile + bi * 16384 + r * 1024;
            gload_lds16(src, dst);
        }
    };
    // txt k 0..255 (1KB/row)
    auto stage_txt1 = [&](int bi) {
        #pragma unroll
        for (int j = 0; j < 4; ++j) {
            int r = wave * 4 + j;
            int swz = (r & 7) << 4;
            const char* src = (const char*)Atxt + (size_t)(row0 + r) * 1536
                              + ((lane * 16) ^ swz);
            char* dst = (char*)atile + bi * 16384 + r * 1024;
            gload_lds16(src, dst);
        }
    };
    // txt k 256..383 (512B/row, 2 rows per inst; 2 insts/wave)
    auto stage_txt2 = [&](int bi) {
        #pragma unroll
        for (int j = 0; j < 2; ++j) {
            int p = wave * 2 + j;
            int r = p * 2 + (lane >> 5);
            int swz = (r & 7) << 4;
            const char* src = (const char*)Atxt + (size_t)(row0 + r) * 1536
                              + 1024 + (((lane & 31) * 16) ^ swz);
            char* dst = (char*)atile + bi * 16384 + p * 1024;
            gload_lds16(src, dst);
        }
    };
    // compute nks k-steps from a staged chunk; B direct from global (L2-hot)
    auto comp = [&](const char* base, int rstride, const short* Wt, int K, int kabs,
                    int nks, f32x4& acc) {
        const int row = col;                      // A-row lane mapping = l&15
        const int swz = (row & 7) << 4;
        const char* ab = base + row * rstride;
        const short* wp = Wt + (size_t)(16 * wave + col) * K + kabs + kb * 8;
        for (int ks = 0; ks < nks; ++ks) {
            int lg = kb * 32 + ks * 128;
            float4 a0 = *(const float4*)(ab + (lg ^ swz));
            float4 a1 = *(const float4*)(ab + ((lg + 16) ^ swz));
            bf16x8 af;
            af[0]=f2bf(a0.x); af[1]=f2bf(a0.y); af[2]=f2bf(a0.z); af[3]=f2bf(a0.w);
            af[4]=f2bf(a1.x); af[5]=f2bf(a1.y); af[6]=f2bf(a1.z); af[7]=f2bf(a1.w);
            bf16x8 bf = *(const bf16x8*)(wp + ks * 32);
            acc = __builtin_amdgcn_mfma_f32_16x16x32_bf16(af, bf, acc, 0, 0, 0);
        }
    };

    f32x4 ai = {0.f,0.f,0.f,0.f}, at4 = {0.f,0.f,0.f,0.f};

    stage_img(0, 0);
    for (int ci = 0; ci < 16; ++ci) {
        int bi = ci & 1;
        if (ci < 15) stage_img(ci + 1, bi ^ 1);
        else         stage_txt1(bi ^ 1);
        asm volatile("s_waitcnt vmcnt(4)" ::: "memory");
        __builtin_amdgcn_s_barrier();
        __builtin_amdgcn_sched_barrier(0);
        comp((const char*)atile + bi * 16384, 1024, Wti, 4096, ci * 256, 8, ai);
        asm volatile("" ::: "memory");
        __builtin_amdgcn_s_barrier();
        __builtin_amdgcn_sched_barrier(0);
    }
    // txt part 1 from buf0 (staged at ci=15); prefetch part 2 into buf1
    stage_txt2(1);
    asm volatile("s_waitcnt vmcnt(2)" ::: "memory");
    __builtin_amdgcn_s_barrier();
    __builtin_amdgcn_sched_barrier(0);
    comp((const char*)atile, 1024, Wtt, 384, 0, 8, at4);
    asm volatile("s_waitcnt vmcnt(0)" ::: "memory");
    __builtin_amdgcn_s_barrier();
    __builtin_amdgcn_sched_barrier(0);
    comp((const char*)atile + 16384, 512, Wtt, 384, 256, 4, at4);

    // ---------------- bias + cross-wave L2 norm + mirror store ----------------
    float bv_i = bimg[16 * wave + col];
    float bv_t = btxt[16 * wave + col];
    float ssi[4], sst[4];
    #pragma unroll
    for (int i = 0; i < 4; ++i) {
        ai[i] += bv_i; at4[i] += bv_t;
        ssi[i] = ai[i] * ai[i];
        sst[i] = at4[i] * at4[i];
    }
    #pragma unroll
    for (int off = 1; off < 16; off <<= 1) {
        #pragma unroll
        for (int i = 0; i < 4; ++i) {
            ssi[i] += __shfl_xor(ssi[i], off, 64);
            sst[i] += __shfl_xor(sst[i], off, 64);
        }
    }
    float* S = (float*)atile;          // [2][4 waves][16 rows]
    __syncthreads();                   // compute reads done; safe to reuse LDS
    if (col == 0) {
        #pragma unroll
        for (int i = 0; i < 4; ++i) {
            S[wave * 16 + kb * 4 + i]      = ssi[i];
            S[64 + wave * 16 + kb * 4 + i] = sst[i];
        }
    }
    __syncthreads();
    unsigned* egob_items = egob + (size_t)N_USERS * 64;
    #pragma unroll
    for (int i = 0; i < 4; ++i) {
        int r = kb * 4 + i;
        float ti = S[r] + S[16 + r] + S[32 + r] + S[48 + r];             // fixed order
        float tt = S[64 + r] + S[80 + r] + S[96 + r] + S[112 + r];
        float rni = 1.0f / fmaxf(sqrtf(ti), 1e-12f);
        float rnt = 1.0f / fmaxf(sqrtf(tt), 1e-12f);
        egob_items[(size_t)(row0 + r) * 64 + 16 * wave + col] =
            pack_bf2(ai[i] * rni, at4[i] * rnt);
    }
}

// ---------------------------------------------------------------- SpMM layer 1 + fused sort

__global__ __launch_bounds__(256) void spmm_sort_kernel(
        const int* __restrict__ cnt, int2* __restrict__ ell,
        const unsigned* __restrict__ xb, unsigned* __restrict__ outb) {
    __shared__ __align__(16) int2 srt[4][ELL_CAP];
    int wid = threadIdx.x >> 6, lane = threadIdx.x & 63;
    int row = blockIdx.x * 4 + wid;
    bool valid = row < N_TOTAL;
    int deg = 0;
    int2* base = nullptr;
    int2 e0 = make_int2(0x7FFFFFFF, 0), e1 = e0;
    if (valid) {
        deg = min(cnt[row], ELL_CAP);
        base = ell + (size_t)row * ELL_CAP;
        if (lane < deg)      e0 = base[lane];
        if (lane + 64 < deg) e1 = base[lane + 64];
    }
    #pragma unroll
    for (int k = 2; k <= 128; k <<= 1) {
        #pragma unroll
        for (int j = 64; j >= 1; j >>= 1) {
            if (j >= k) continue;
            if (j == 64) {
                if (e0.x > e1.x) { int2 tmp = e0; e0 = e1; e1 = tmp; }
            } else {
                int2 p0, p1;
                p0.x = __shfl_xor(e0.x, j, 64); p0.y = __shfl_xor(e0.y, j, 64);
                p1.x = __shfl_xor(e1.x, j, 64); p1.y = __shfl_xor(e1.y, j, 64);
                bool up0 = ((lane & k) == 0);
                bool up1 = (((lane + 64) & k) == 0);
                bool lo0 = ((lane & j) == 0);
                bool keepmin0 = (up0 == lo0);
                bool keepmin1 = (up1 == lo0);
                if (keepmin0 ? (e0.x > p0.x) : (e0.x < p0.x)) e0 = p0;
                if (keepmin1 ? (e1.x > p1.x) : (e1.x < p1.x)) e1 = p1;
            }
        }
    }
    if (valid) {
        if (lane < deg)      base[lane]      = e0;
        if (lane + 64 < deg) base[lane + 64] = e1;
    }
    srt[wid][lane] = e0;
    srt[wid][lane + 64] = e1;
    __syncthreads();
    if (!valid) return;
    unsigned sw = xb[(size_t)row * 64 + lane];
    float2 acc;
    acc.x = ALPHA_F * bf_lo(sw);
    acc.y = ALPHA_F * bf_hi(sw);
    const int2* s = srt[wid];
    int i = 0;
    for (; i + 8 <= deg; i += 8) {
        int4 p0 = *reinterpret_cast<const int4*>(s + i);
        int4 p1 = *reinterpret_cast<const int4*>(s + i + 2);
        int4 p2 = *reinterpret_cast<const int4*>(s + i + 4);
        int4 p3 = *reinterpret_cast<const int4*>(s + i + 6);
        unsigned g0 = xb[(size_t)p0.x * 64 + lane];
        unsigned g1 = xb[(size_t)p0.z * 64 + lane];
        unsigned g2 = xb[(size_t)p1.x * 64 + lane];
        unsigned g3 = xb[(size_t)p1.z * 64 + lane];
        unsigned g4 = xb[(size_t)p2.x * 64 + lane];
        unsigned g5 = xb[(size_t)p2.z * 64 + lane];
        unsigned g6 = xb[(size_t)p3.x * 64 + lane];
        unsigned g7 = xb[(size_t)p3.z * 64 + lane];
        float v0 = __int_as_float(p0.y), v1 = __int_as_float(p0.w);
        float v2 = __int_as_float(p1.y), v3 = __int_as_float(p1.w);
        float v4 = __int_as_float(p2.y), v5 = __int_as_float(p2.w);
        float v6 = __int_as_float(p3.y), v7 = __int_as_float(p3.w);
        acc.x = fmaf(v0, bf_lo(g0), acc.x); acc.y = fmaf(v0, bf_hi(g0), acc.y);
        acc.x = fmaf(v1, bf_lo(g1), acc.x); acc.y = fmaf(v1, bf_hi(g1), acc.y);
        acc.x = fmaf(v2, bf_lo(g2), acc.x); acc.y = fmaf(v2, bf_hi(g2), acc.y);
        acc.x = fmaf(v3, bf_lo(g3), acc.x); acc.y = fmaf(v3, bf_hi(g3), acc.y);
        acc.x = fmaf(v4, bf_lo(g4), acc.x); acc.y = fmaf(v4, bf_hi(g4), acc.y);
        acc.x = fmaf(v5, bf_lo(g5), acc.x); acc.y = fmaf(v5, bf_hi(g5), acc.y);
        acc.x = fmaf(v6, bf_lo(g6), acc.x); acc.y = fmaf(v6, bf_hi(g6), acc.y);
        acc.x = fmaf(v7, bf_lo(g7), acc.x); acc.y = fmaf(v7, bf_hi(g7), acc.y);
    }
    for (; i < deg; ++i) {
        int2 c = s[i];
        float v = __int_as_float(c.y);
        unsigned g = xb[(size_t)c.x * 64 + lane];
        acc.x = fmaf(v, bf_lo(g), acc.x);
        acc.y = fmaf(v, bf_hi(g), acc.y);
    }
    outb[(size_t)row * 64 + lane] = pack_bf2(acc.x, acc.y);
}

// ---------------------------------------------------------------- SpMM layers 2-3

__global__ __launch_bounds__(256) void spmm_kernel(
        const int* __restrict__ cnt, const int2* __restrict__ ell,
        const unsigned* __restrict__ xb,
        float* __restrict__ out32, unsigned* __restrict__ outb) {
    int row = blockIdx.x * 4 + (threadIdx.x >> 6);
    if (row >= N_TOTAL) return;
    int lane = threadIdx.x & 63;
    unsigned sw = xb[(size_t)row * 64 + lane];
    float2 acc;
    acc.x = ALPHA_F * bf_lo(sw);
    acc.y = ALPHA_F * bf_hi(sw);
    int deg = min(cnt[row], ELL_CAP);
    const int2* base = ell + (size_t)row * ELL_CAP;
    int i = 0;
    for (; i + 8 <= deg; i += 8) {
        int4 p0 = *reinterpret_cast<const int4*>(base + i);
        int4 p1 = *reinterpret_cast<const int4*>(base + i + 2);
        int4 p2 = *reinterpret_cast<const int4*>(base + i + 4);
        int4 p3 = *reinterpret_cast<const int4*>(base + i + 6);
        unsigned g0 = xb[(size_t)p0.x * 64 + lane];
        unsigned g1 = xb[(size_t)p0.z * 64 + lane];
        unsigned g2 = xb[(size_t)p1.x * 64 + lane];
        unsigned g3 = xb[(size_t)p1.z * 64 + lane];
        unsigned g4 = xb[(size_t)p2.x * 64 + lane];
        unsigned g5 = xb[(size_t)p2.z * 64 + lane];
        unsigned g6 = xb[(size_t)p3.x * 64 + lane];
        unsigned g7 = xb[(size_t)p3.z * 64 + lane];
        float v0 = __int_as_float(p0.y), v1 = __int_as_float(p0.w);
        float v2 = __int_as_float(p1.y), v3 = __int_as_float(p1.w);
        float v4 = __int_as_float(p2.y), v5 = __int_as_float(p2.w);
        float v6 = __int_as_float(p3.y), v7 = __int_as_float(p3.w);
        acc.x = fmaf(v0, bf_lo(g0), acc.x); acc.y = fmaf(v0, bf_hi(g0), acc.y);
        acc.x = fmaf(v1, bf_lo(g1), acc.x); acc.y = fmaf(v1, bf_hi(g1), acc.y);
        acc.x = fmaf(v2, bf_lo(g2), acc.x); acc.y = fmaf(v2, bf_hi(g2), acc.y);
        acc.x = fmaf(v3, bf_lo(g3), acc.x); acc.y = fmaf(v3, bf_hi(g3), acc.y);
        acc.x = fmaf(v4, bf_lo(g4), acc.x); acc.y = fmaf(v4, bf_hi(g4), acc.y);
        acc.x = fmaf(v5, bf_lo(g5), acc.x); acc.y = fmaf(v5, bf_hi(g5), acc.y);
        acc.x = fmaf(v6, bf_lo(g6), acc.x); acc.y = fmaf(v6, bf_hi(g6), acc.y);
        acc.x = fmaf(v7, bf_lo(g7), acc.x); acc.y = fmaf(v7, bf_hi(g7), acc.y);
    }
    for (; i < deg; ++i) {
        int2 c = base[i];
        float v = __int_as_float(c.y);
        unsigned g = xb[(size_t)c.x * 64 + lane];
        acc.x = fmaf(v, bf_lo(g), acc.x);
        acc.y = fmaf(v, bf_hi(g), acc.y);
    }
    if (out32) {
        out32[(size_t)row * 128 + lane] = acc.x;
        out32[(size_t)row * 128 + 64 + lane] = acc.y;
    }
    if (outb)
        outb[(size_t)row * 64 + lane] = pack_bf2(acc.x, acc.y);
}

// ---------------------------------------------------------------- launch

extern "C" void kernel_launch(void* const* d_in, const int* in_sizes, int n_in,
                              void* d_out, int out_size, void* d_ws, size_t ws_size,
                              hipStream_t stream) {
    const float* image_feats = (const float*)d_in[0];
    const float* text_feats  = (const float*)d_in[1];
    const float* image_pref  = (const float*)d_in[2];
    const float* text_pref   = (const float*)d_in[3];
    const float* W_img       = (const float*)d_in[4];
    const float* b_img       = (const float*)d_in[5];
    const float* W_txt       = (const float*)d_in[6];
    const float* b_txt       = (const float*)d_in[7];
    const float* adj_vals    = (const float*)d_in[8];
    const int*   adj_rows    = (const int*)d_in[9];
    const int*   adj_cols    = (const int*)d_in[10];

    float* out = (float*)d_out;                          // [150000*128]

    char* ws = (char*)d_ws;
    size_t off = 0;
    auto alloc = [&](size_t bytes) { char* p = ws + off; off += (bytes + 255) & ~size_t(255); return p; };
    int*      cnt    = (int*)     alloc(N_TOTAL * sizeof(int));
    int2*     ell    = (int2*)    alloc((size_t)N_TOTAL * ELL_CAP * sizeof(int2));
    unsigned* m0     = (unsigned*)alloc((size_t)N_TOTAL * 64 * sizeof(unsigned));
    unsigned* m1     = (unsigned*)alloc((size_t)N_TOTAL * 64 * sizeof(unsigned));
    short*    Wt_img = (short*)   alloc((size_t)64 * 4096 * sizeof(short));
    short*    Wt_txt = (short*)   alloc((size_t)64 * 384 * sizeof(short));
    (void)ws_size; (void)out_size; (void)n_in; (void)in_sizes;

    // --- prep: zero cnt + bf16 W transposes ---
    prep_kernel<<<512, 256, 0, stream>>>(W_img, W_txt, cnt, Wt_img, Wt_txt);

    // --- mega: scatter || copy || GEMM (scatter/copy first for co-residency) ---
    mega_kernel<<<G_PRE + G_GEMM, 256, 0, stream>>>(
        image_feats, text_feats, Wt_img, Wt_txt, b_img, b_txt, m0,
        adj_rows, adj_cols, adj_vals, cnt, ell, image_pref, text_pref);

    // --- layer 1 (+ canonical in-kernel sort), then layers 2-3 ---
    const int ROW_GRID = (N_TOTAL + 3) / 4;
    spmm_sort_kernel<<<ROW_GRID, 256, 0, stream>>>(cnt, ell, m0, m1);
    spmm_kernel<<<ROW_GRID, 256, 0, stream>>>(cnt, ell, m1, nullptr, m0);
    spmm_kernel<<<ROW_GRID, 256, 0, stream>>>(cnt, ell, m0, out, nullptr);
}